// Round 3
// baseline (192.058 us; speedup 1.0000x reference)
//
#include <hip/hip_runtime.h>

typedef _Float16 half4 __attribute__((ext_vector_type(4)));
typedef _Float16 half8 __attribute__((ext_vector_type(8)));
typedef _Float16 h2pk __attribute__((ext_vector_type(2)));
typedef float f32x4 __attribute__((ext_vector_type(4)));

#define MFMA_F16K32(a, b, c) __builtin_amdgcn_mfma_f32_16x16x32_f16(a, b, c, 0, 0, 0)
#define MFMA_F16K16(a, b, c) __builtin_amdgcn_mfma_f32_16x16x16f16(a, b, c, 0, 0, 0)
#define EXP2F(x) __builtin_amdgcn_exp2f(x)
#define CVT_PK(a, b) __builtin_bit_cast(h2pk, __builtin_amdgcn_cvt_pkrtz(a, b))

constexpr int NSEQ = 2048, DIM = 1024;
constexpr int MROWS = 4096;
constexpr float QSCALE = 11.5415603271f;  // 8 * log2(e): logits in log2 units

__device__ __forceinline__ void ld_lds16(void* lds, const void* g) {
  __builtin_amdgcn_global_load_lds(
      (const __attribute__((address_space(1))) void*)g,
      (__attribute__((address_space(3))) void*)lds, 16, 0, 0);
}

// ---------------------------------------------------------------------------
// prep: blocks 0..1023 transpose weights 64x64 -> fp16 WT[3072][1024] / WoT;
// blocks 1024..3071: x -> fp16.
// ---------------------------------------------------------------------------
__global__ __launch_bounds__(256) void prep(
    const float* __restrict__ w_q, const float* __restrict__ w_vk,
    const float* __restrict__ w_out, const float* __restrict__ x,
    _Float16* __restrict__ WT, _Float16* __restrict__ WoT,
    _Float16* __restrict__ xf) {
  const int bid = blockIdx.x;
  const int t = threadIdx.x;
  if (bid >= 1024) {  // ---- x -> fp16 ----
    const size_t i = ((size_t)(bid - 1024) * 256 + t) * 8;
    float4 a = *(const float4*)(x + i), b2 = *(const float4*)(x + i + 4);
    float v[8] = {a.x, a.y, a.z, a.w, b2.x, b2.y, b2.z, b2.w};
    half8 h;
#pragma unroll
    for (int j = 0; j < 8; ++j) h[j] = (_Float16)v[j];
    *(half8*)(xf + i) = h;
    return;
  }
  __shared__ float T[64][65];
  const int bx = bid & 63, k0 = (bid >> 6) * 64;
  const float* src;
  int srcN, n0, dstrow, mode;
  float scale;
  if (bx < 16) {
    src = w_q; srcN = 1024; n0 = bx * 64; dstrow = n0; scale = QSCALE; mode = 0;
  } else if (bx < 48) {
    src = w_vk; srcN = 2048; n0 = (bx - 16) * 64; dstrow = 1024 + n0;
    scale = 1.0f; mode = 0;
  } else {
    src = w_out; srcN = 1024; n0 = (bx - 48) * 64; dstrow = n0;
    scale = 1.0f; mode = 1;
  }
  {
    const int r = t >> 2, c4 = (t & 3) * 16;
    const float* s = src + (size_t)(k0 + r) * srcN + n0 + c4;
    float4 v0 = ((const float4*)s)[0], v1 = ((const float4*)s)[1],
           v2 = ((const float4*)s)[2], v3 = ((const float4*)s)[3];
    *(float4*)&T[r][c4 + 0] = v0;  *(float4*)&T[r][c4 + 4] = v1;
    *(float4*)&T[r][c4 + 8] = v2;  *(float4*)&T[r][c4 + 12] = v3;
  }
  __syncthreads();
  const int rn = t >> 2, kc = (t & 3) * 16;
  half8 hv[2];
#pragma unroll
  for (int half = 0; half < 2; ++half)
#pragma unroll
    for (int j = 0; j < 8; ++j)
      hv[half][j] = (_Float16)(T[kc + half * 8 + j][rn] * scale);
  _Float16* d = ((mode == 0) ? WT + (size_t)(dstrow + rn) * 1024
                             : WoT + (size_t)(n0 + rn) * 1024) + k0 + kc;
  *(half8*)d = hv[0]; *(half8*)(d + 8) = hv[1];
}

// ---------------------------------------------------------------------------
// Fused q/k/v projection, all fp16 single-product. 128x128 tile, BK=32,
// double-buffered 2x16KB, ONE barrier per K-iter, 3 blocks/CU.
// kind = bn>>10: 0 -> qb [tok][1024] (weights pre-scaled by QSCALE);
// 1 -> kb [tok][1024]; 2 -> vT fp16 [b][h][d][n].
// ---------------------------------------------------------------------------
__global__ __launch_bounds__(256, 3) void proj6(
    const _Float16* __restrict__ xf, const _Float16* __restrict__ WT,
    _Float16* __restrict__ qb, _Float16* __restrict__ kb,
    _Float16* __restrict__ VT) {
  __shared__ __align__(16) char smem[32768];  // 2 bufs x (X 8KB | B 8KB)
  const int t = threadIdx.x;
  const int lane = t & 63, wave = t >> 6, quad = lane >> 4, lq = lane & 15;
  const int bn = blockIdx.x * 128, bm = blockIdx.y * 128;
  const int kind = bn >> 10;
  const int wm = (wave >> 1) * 64, wn = (wave & 1) * 64;

  // staging: 64B rows (32 fp16); one 1KB issue = 16 rows, 4 lanes/row.
  const int srow = lane >> 2;                // 0..15
  const int schk = (lane & 3) ^ (srow & 3);  // 16B chunk
  const _Float16* xg = xf + (size_t)(bm + wave * 32 + srow) * DIM + schk * 8;
  const _Float16* bg = WT + (size_t)(bn + wave * 32 + srow) * DIM + schk * 8;
  const int wb = wave * 2048;  // 32 rows x 64B

  auto issue = [&](char* buf, int k0) {
    ld_lds16(buf + wb,                xg + k0);
    ld_lds16(buf + wb + 1024,         xg + k0 + 16 * DIM);
    ld_lds16(buf + 8192 + wb,         bg + k0);
    ld_lds16(buf + 8192 + wb + 1024,  bg + k0 + 16 * DIM);
  };

  const int swz = (quad ^ (lq & 3)) * 8;  // chunk c of row r at c^(r&3)

  f32x4 acc[4][4];
#pragma unroll
  for (int i = 0; i < 4; ++i)
#pragma unroll
    for (int j = 0; j < 4; ++j) acc[i][j] = (f32x4){0.f, 0.f, 0.f, 0.f};

  char* bufA = smem;
  char* bufB = smem + 16384;
  issue(bufA, 0);
  for (int k0 = 0; k0 < DIM; k0 += 32) {
    char* cur = ((k0 >> 5) & 1) ? bufB : bufA;
    char* nxt = ((k0 >> 5) & 1) ? bufA : bufB;
    __syncthreads();  // drain DMA for cur; all waves done reading nxt
    if (k0 + 32 < DIM) issue(nxt, k0 + 32);
    const _Float16* Xs = (const _Float16*)cur;
    const _Float16* Bs = (const _Float16*)(cur + 8192);
    half8 ah[4];
#pragma unroll
    for (int i = 0; i < 4; ++i)
      ah[i] = *(const half8*)&Xs[(wm + i * 16 + lq) * 32 + swz];
#pragma unroll
    for (int j = 0; j < 4; ++j) {
      half8 bf = *(const half8*)&Bs[(wn + j * 16 + lq) * 32 + swz];
#pragma unroll
      for (int i = 0; i < 4; ++i) acc[i][j] = MFMA_F16K32(ah[i], bf, acc[i][j]);
    }
  }

  if (kind == 2) {  // v -> vT[b][h][d][n], 4 consecutive tokens / 8B store
#pragma unroll
    for (int i = 0; i < 4; ++i)
#pragma unroll
      for (int j = 0; j < 4; ++j) {
        const int c = (bn - 2048) + wn + j * 16 + lq;  // h*64 + d
        const int row0 = bm + wm + i * 16 + quad * 4;  // token
        const int b = row0 >> 11, n = row0 & 2047;
        const int h = c >> 6, d = c & 63;
        half4 o;
#pragma unroll
        for (int r = 0; r < 4; ++r) o[r] = (_Float16)acc[i][j][r];
        *(half4*)(VT + ((size_t)(b * 16 + h) * 64 + d) * 2048 + n) = o;
      }
  } else {
    _Float16* D = (kind == 0) ? qb : kb;
    const int cb = bn & 1023;
#pragma unroll
    for (int i = 0; i < 4; ++i)
#pragma unroll
      for (int j = 0; j < 4; ++j) {
        const int col = cb + wn + j * 16 + lq;
#pragma unroll
        for (int r = 0; r < 4; ++r) {
          const int row = bm + wm + i * 16 + quad * 4 + r;
          D[(size_t)row * 1024 + col] = (_Float16)acc[i][j][r];
        }
      }
  }
}

// ---------------------------------------------------------------------------
// Flash attention, all fp16 single-product. TI=128, 8 waves x 16 q-rows
// (512 threads) -> 16 waves/CU (2 blocks x 64KB LDS) = 4 waves/SIMD, double
// the latency hiding of the 4-wave version. TJ=128, double-buffered 2x32KB
// DMA staging, ONE barrier per 128-key iter. Softmax merged to a SINGLE
// online update per 128-key tile (was 2x per-64 halves): one max-reduce, one
// alpha exp2, one o-rescale. Packed f16 cvt via v_cvt_pkrtz; setprio(1)
// around MFMA clusters.
// ---------------------------------------------------------------------------
__global__ __launch_bounds__(512, 4) void attn7(
    const _Float16* __restrict__ qb, const _Float16* __restrict__ kb,
    const _Float16* __restrict__ vT, _Float16* __restrict__ ho) {
  __shared__ __align__(16) char smem[65536];  // 2 bufs: K 16KB | V 16KB
  const int t = threadIdx.x;
  const int lane = t & 63, wave = t >> 6, quad = lane >> 4, lq = lane & 15;
  const int i0 = blockIdx.x * 128;
  const int bh = blockIdx.y, b = bh >> 4, head = bh & 15;
  const size_t rowbase = (size_t)b * NSEQ;

  // Q fragments (B-operand layout), contiguous 16B loads; 16 rows per wave
  half8 qf0, qf1;
  {
    const _Float16* qp =
        qb + (rowbase + i0 + wave * 16 + lq) * DIM + head * 64 + quad * 8;
    qf0 = *(const half8*)qp;
    qf1 = *(const half8*)(qp + 32);
  }

  f32x4 o[4];
#pragma unroll
  for (int dt = 0; dt < 4; ++dt) o[dt] = (f32x4){0.f, 0.f, 0.f, 0.f};
  float mrun = -3.0e38f;
  float lrun = 0.f;

  // K staging: 128 rows x 128B; wave stages rows wave*16..+15 (2 issues).
  const int srow = lane >> 3, schk = (lane & 7) ^ srow;
  const _Float16* kg =
      kb + (rowbase + wave * 16 + srow) * DIM + head * 64 + schk * 8;
  // V staging: 64 d-rows x 256B; wave stages rows wave*8..+7 (2 issues).
  const int vr = lane >> 4;
  int vco[2];
#pragma unroll
  for (int is = 0; is < 2; ++is)
    vco[is] = ((lane & 15) ^ ((wave & 1) * 8 + is * 4 + vr)) * 8;
  const _Float16* vg = vT + ((size_t)bh * 64 + wave * 8 + vr) * NSEQ;

  auto issue = [&](char* buf, int j0) {
#pragma unroll
    for (int is = 0; is < 2; ++is) {
      ld_lds16(buf + wave * 2048 + is * 1024,
               kg + ((size_t)j0 + is * 8) * DIM);
      ld_lds16(buf + 16384 + (wave * 8 + is * 4) * 256,
               vg + (size_t)is * 4 * NSEQ + j0 + vco[is]);
    }
  };

  const int swzK0 = (quad ^ (lq & 7)) * 8;        // chunk c of row r at c^(r&7)
  const int swzK1 = ((quad + 4) ^ (lq & 7)) * 8;

  char* bufA = smem;
  char* bufB = smem + 32768;
  issue(bufA, 0);

  for (int j0 = 0; j0 < NSEQ; j0 += 128) {
    char* cur = ((j0 >> 7) & 1) ? bufB : bufA;
    char* nxt = ((j0 >> 7) & 1) ? bufA : bufB;
    __syncthreads();  // drain cur's DMA; all waves done reading nxt
    if (j0 + 128 < NSEQ) issue(nxt, j0 + 128);
    const _Float16* Khs = (const _Float16*)cur;            // [128][64 elems]
    const _Float16* Vts = (const _Float16*)(cur + 16384);  // [64][128 elems]

    // S^T = K.Q^T for all 128 keys of the tile (single f16 product)
    f32x4 s[8];
    __builtin_amdgcn_s_setprio(1);
#pragma unroll
    for (int nt = 0; nt < 8; ++nt) {
      const int roff = (nt * 16 + lq) * 64;
      half8 k0f = *(const half8*)&Khs[roff + swzK0];
      half8 k1f = *(const half8*)&Khs[roff + swzK1];
      f32x4 sv = (f32x4){0.f, 0.f, 0.f, 0.f};
      sv = MFMA_F16K32(k0f, qf0, sv);
      sv = MFMA_F16K32(k1f, qf1, sv);
      s[nt] = sv;
    }
    __builtin_amdgcn_s_setprio(0);

    // ONE online-softmax update per 128-key tile; q-rows lane-resident.
    float mx;
    {
      // max3-friendly tree over the 32 lane-resident scores
      float m0 = fmaxf(fmaxf(s[0][0], s[0][1]), fmaxf(s[0][2], s[0][3]));
      float m1 = fmaxf(fmaxf(s[1][0], s[1][1]), fmaxf(s[1][2], s[1][3]));
      float m2 = fmaxf(fmaxf(s[2][0], s[2][1]), fmaxf(s[2][2], s[2][3]));
      float m3 = fmaxf(fmaxf(s[3][0], s[3][1]), fmaxf(s[3][2], s[3][3]));
      float m4 = fmaxf(fmaxf(s[4][0], s[4][1]), fmaxf(s[4][2], s[4][3]));
      float m5 = fmaxf(fmaxf(s[5][0], s[5][1]), fmaxf(s[5][2], s[5][3]));
      float m6 = fmaxf(fmaxf(s[6][0], s[6][1]), fmaxf(s[6][2], s[6][3]));
      float m7 = fmaxf(fmaxf(s[7][0], s[7][1]), fmaxf(s[7][2], s[7][3]));
      mx = fmaxf(fmaxf(fmaxf(m0, m1), fmaxf(m2, m3)),
                 fmaxf(fmaxf(m4, m5), fmaxf(m6, m7)));
    }
    mx = fmaxf(mx, __shfl_xor(mx, 16));
    mx = fmaxf(mx, __shfl_xor(mx, 32));
    const float mn = fmaxf(mrun, mx);
    const float alpha = EXP2F(mrun - mn);
    mrun = mn;
    float rs = 0.f;
    half4 pb[8];
#pragma unroll
    for (int nt = 0; nt < 8; ++nt) {
      float p0 = EXP2F(s[nt][0] - mn), p1 = EXP2F(s[nt][1] - mn);
      float p2 = EXP2F(s[nt][2] - mn), p3 = EXP2F(s[nt][3] - mn);
      rs += (p0 + p1) + (p2 + p3);
      h2pk lo = CVT_PK(p0, p1);
      h2pk hi = CVT_PK(p2, p3);
      pb[nt] = (half4){lo[0], lo[1], hi[0], hi[1]};
    }
    rs += __shfl_xor(rs, 16);
    rs += __shfl_xor(rs, 32);
    lrun = lrun * alpha + rs;
#pragma unroll
    for (int dt = 0; dt < 4; ++dt) o[dt] *= alpha;

    // O^T += V^T . P^T  (P^T straight from C-layout registers)
    __builtin_amdgcn_s_setprio(1);
#pragma unroll
    for (int dt = 0; dt < 4; ++dt) {
      const int vrow = (dt * 16 + lq) * 128;
#pragma unroll
      for (int ntj = 0; ntj < 8; ++ntj) {
        const int voff =
            vrow + ((2 * ntj + (quad >> 1)) ^ lq) * 8 + (quad & 1) * 4;
        half4 va = *(const half4*)&Vts[voff];
        o[dt] = MFMA_F16K16(va, pb[ntj], o[dt]);
      }
    }
    __builtin_amdgcn_s_setprio(0);
  }

  // epilogue: O^T -> LDS transpose (pitch 80 f16) -> coalesced store
  _Float16* Ots = (_Float16*)smem;
  __syncthreads();  // all waves done with final tile reads
  {
    const float inv = 1.0f / lrun;
#pragma unroll
    for (int dt = 0; dt < 4; ++dt)
#pragma unroll
      for (int r = 0; r < 4; ++r)
        Ots[(wave * 16 + lq) * 80 + dt * 16 + quad * 4 + r] =
            (_Float16)(o[dt][r] * inv);
  }
  __syncthreads();
  {
    const int row = t >> 2, seg = t & 3;
    const _Float16* src = &Ots[row * 80 + seg * 16];
    half8 o0 = ((const half8*)src)[0], o1 = ((const half8*)src)[1];
    _Float16* dst = ho + (rowbase + i0 + row) * DIM + head * 64 + seg * 16;
    ((half8*)dst)[0] = o0; ((half8*)dst)[1] = o1;
  }
}

// ---------------------------------------------------------------------------
// out = ho(fp16) @ w_out — double-buffered, one barrier per K-iter.
// ---------------------------------------------------------------------------
__global__ __launch_bounds__(256, 4) void gemm_out(
    const _Float16* __restrict__ A, const _Float16* __restrict__ BT,
    float* __restrict__ C) {
  __shared__ __align__(16) char smem[24576];  // 2 bufs: A 4KB | B 8KB
  const int t = threadIdx.x;
  const int lane = t & 63, wave = t >> 6, quad = lane >> 4, lq = lane & 15;
  const int bn = blockIdx.x * 128, bm = blockIdx.y * 64;
  const int wm = (wave >> 1) * 32, wn = (wave & 1) * 64;

  const int bco = (lane & 7) ^ (lane >> 3);
  const int brow = 2 * (lane >> 3) + (bco >> 2);
  const int bcc = bco & 3;
  const _Float16* ag = A + (size_t)(bm + wave * 16 + brow) * DIM + bcc * 8;
  const _Float16* bg = BT + (size_t)(bn + wave * 32 + brow) * DIM + bcc * 8;
  const int swzB = ((((lq & 1) << 2) | quad) ^ ((lq >> 1) & 7)) * 8;

  auto issue = [&](char* buf, int k0) {
    ld_lds16(buf + wave * 1024,               ag + k0);
    ld_lds16(buf + 4096 + wave * 2048,        bg + k0);
    ld_lds16(buf + 4096 + wave * 2048 + 1024, bg + k0 + 16 * DIM);
  };

  f32x4 acc[2][4];
#pragma unroll
  for (int i = 0; i < 2; ++i)
#pragma unroll
    for (int j = 0; j < 4; ++j) acc[i][j] = (f32x4){0.f, 0.f, 0.f, 0.f};

  char* bufA = smem;
  char* bufB = smem + 12288;
  issue(bufA, 0);
  for (int k0 = 0; k0 < DIM; k0 += 32) {
    char* cur = ((k0 >> 5) & 1) ? bufB : bufA;
    char* nxt = ((k0 >> 5) & 1) ? bufA : bufB;
    __syncthreads();
    if (k0 + 32 < DIM) issue(nxt, k0 + 32);
    const _Float16* Ahs = (const _Float16*)cur;
    const _Float16* Bhs = (const _Float16*)(cur + 4096);
    half8 ah[2];
#pragma unroll
    for (int i = 0; i < 2; ++i) {
      const int row = wm + i * 16 + lq;
      ah[i] = *(const half8*)&Ahs[(row >> 1) * 64 + swzB];
    }
#pragma unroll
    for (int j = 0; j < 4; ++j) {
      const int row = wn + j * 16 + lq;
      half8 bf = *(const half8*)&Bhs[(row >> 1) * 64 + swzB];
#pragma unroll
      for (int i = 0; i < 2; ++i) acc[i][j] = MFMA_F16K32(ah[i], bf, acc[i][j]);
    }
  }
#pragma unroll
  for (int i = 0; i < 2; ++i)
#pragma unroll
    for (int j = 0; j < 4; ++j) {
      const int col = bn + wn + j * 16 + lq;
#pragma unroll
      for (int r = 0; r < 4; ++r) {
        const int row = bm + wm + i * 16 + quad * 4 + r;
        C[(size_t)row * 1024 + col] = acc[i][j][r];
      }
    }
}

// ---------------------------------------------------------------------------
extern "C" void kernel_launch(void* const* d_in, const int* in_sizes, int n_in,
                              void* d_out, int out_size, void* d_ws,
                              size_t ws_size, hipStream_t stream) {
  const float* x     = (const float*)d_in[0];
  const float* w_q   = (const float*)d_in[1];
  const float* w_vk  = (const float*)d_in[2];
  const float* w_out = (const float*)d_in[3];
  float* out = (float*)d_out;

  char* w = (char*)d_ws;  // 48 MB used
  _Float16* wT  = (_Float16*)(w);                  // [3072][1024] 6MB
  _Float16* woT = (_Float16*)(w + (6ull << 20));   // [1024][1024] 2MB
  _Float16* qbb = (_Float16*)(w + (8ull << 20));   // [4096][1024] 8MB
  _Float16* kbb = (_Float16*)(w + (16ull << 20));  // [4096][1024] 8MB
  _Float16* vTb = (_Float16*)(w + (24ull << 20));  // [b][h][64][2048] 8MB
  _Float16* hob = (_Float16*)(w + (32ull << 20));  // [4096][1024] 8MB
  _Float16* xfb = (_Float16*)(w + (40ull << 20));  // [4096][1024] 8MB

  dim3 blk(256);
  prep<<<dim3(3072), blk, 0, stream>>>(w_q, w_vk, w_out, x, wT, woT, xfb);
  proj6<<<dim3(24, 32), blk, 0, stream>>>(xfb, wT, qbb, kbb, vTb);
  attn7<<<dim3(16, 32), dim3(512), 0, stream>>>(qbb, kbb, vTb, hob);
  gemm_out<<<dim3(8, 64), blk, 0, stream>>>(hob, woT, out);
}

// Round 4
// 189.131 us; speedup vs baseline: 1.0155x; 1.0155x over previous
//
#include <hip/hip_runtime.h>

typedef _Float16 half4 __attribute__((ext_vector_type(4)));
typedef _Float16 half8 __attribute__((ext_vector_type(8)));
typedef _Float16 h2pk __attribute__((ext_vector_type(2)));
typedef float f32x4 __attribute__((ext_vector_type(4)));

#define MFMA_F16K32(a, b, c) __builtin_amdgcn_mfma_f32_16x16x32_f16(a, b, c, 0, 0, 0)
#define MFMA_F16K16(a, b, c) __builtin_amdgcn_mfma_f32_16x16x16f16(a, b, c, 0, 0, 0)
#define EXP2F(x) __builtin_amdgcn_exp2f(x)
#define CVT_PK(a, b) __builtin_bit_cast(h2pk, __builtin_amdgcn_cvt_pkrtz(a, b))

constexpr int NSEQ = 2048, DIM = 1024;
constexpr float QSCALE = 11.5415603271f;  // 8 * log2(e): logits in log2 units

__device__ __forceinline__ void ld_lds16(void* lds, const void* g) {
  __builtin_amdgcn_global_load_lds(
      (const __attribute__((address_space(1))) void*)g,
      (__attribute__((address_space(3))) void*)lds, 16, 0, 0);
}

// ---------------------------------------------------------------------------
// prep: blocks 0..1023 transpose weights 64x64 -> fp16 WT[3072][1024] / WoT;
// blocks 1024..3071: x -> fp16.
// ---------------------------------------------------------------------------
__global__ __launch_bounds__(256) void prep(
    const float* __restrict__ w_q, const float* __restrict__ w_vk,
    const float* __restrict__ w_out, const float* __restrict__ x,
    _Float16* __restrict__ WT, _Float16* __restrict__ WoT,
    _Float16* __restrict__ xf) {
  const int bid = blockIdx.x;
  const int t = threadIdx.x;
  if (bid >= 1024) {  // ---- x -> fp16 ----
    const size_t i = ((size_t)(bid - 1024) * 256 + t) * 8;
    float4 a = *(const float4*)(x + i), b2 = *(const float4*)(x + i + 4);
    float v[8] = {a.x, a.y, a.z, a.w, b2.x, b2.y, b2.z, b2.w};
    half8 h;
#pragma unroll
    for (int j = 0; j < 8; ++j) h[j] = (_Float16)v[j];
    *(half8*)(xf + i) = h;
    return;
  }
  __shared__ float T[64][65];
  const int bx = bid & 63, k0 = (bid >> 6) * 64;
  const float* src;
  int srcN, n0, dstrow, mode;
  float scale;
  if (bx < 16) {
    src = w_q; srcN = 1024; n0 = bx * 64; dstrow = n0; scale = QSCALE; mode = 0;
  } else if (bx < 48) {
    src = w_vk; srcN = 2048; n0 = (bx - 16) * 64; dstrow = 1024 + n0;
    scale = 1.0f; mode = 0;
  } else {
    src = w_out; srcN = 1024; n0 = (bx - 48) * 64; dstrow = n0;
    scale = 1.0f; mode = 1;
  }
  {
    const int r = t >> 2, c4 = (t & 3) * 16;
    const float* s = src + (size_t)(k0 + r) * srcN + n0 + c4;
    float4 v0 = ((const float4*)s)[0], v1 = ((const float4*)s)[1],
           v2 = ((const float4*)s)[2], v3 = ((const float4*)s)[3];
    *(float4*)&T[r][c4 + 0] = v0;  *(float4*)&T[r][c4 + 4] = v1;
    *(float4*)&T[r][c4 + 8] = v2;  *(float4*)&T[r][c4 + 12] = v3;
  }
  __syncthreads();
  const int rn = t >> 2, kc = (t & 3) * 16;
  half8 hv[2];
#pragma unroll
  for (int half = 0; half < 2; ++half)
#pragma unroll
    for (int j = 0; j < 8; ++j)
      hv[half][j] = (_Float16)(T[kc + half * 8 + j][rn] * scale);
  _Float16* d = ((mode == 0) ? WT + (size_t)(dstrow + rn) * 1024
                             : WoT + (size_t)(n0 + rn) * 1024) + k0 + kc;
  *(half8*)d = hv[0]; *(half8*)(d + 8) = hv[1];
}

// ---------------------------------------------------------------------------
// Fused q/k/v projection, all fp16 single-product. 128x128 tile, BK=32,
// double-buffered 2x16KB, ONE barrier per K-iter, 3 blocks/CU.
// kind = bn>>10: 0 -> qb [tok][1024] (weights pre-scaled by QSCALE);
// 1 -> kb [tok][1024]; 2 -> vT fp16 [b][h][d][n].
// ---------------------------------------------------------------------------
__global__ __launch_bounds__(256, 3) void proj6(
    const _Float16* __restrict__ xf, const _Float16* __restrict__ WT,
    _Float16* __restrict__ qb, _Float16* __restrict__ kb,
    _Float16* __restrict__ VT) {
  __shared__ __align__(16) char smem[32768];  // 2 bufs x (X 8KB | B 8KB)
  const int t = threadIdx.x;
  const int lane = t & 63, wave = t >> 6, quad = lane >> 4, lq = lane & 15;
  const int bn = blockIdx.x * 128, bm = blockIdx.y * 128;
  const int kind = bn >> 10;
  const int wm = (wave >> 1) * 64, wn = (wave & 1) * 64;

  // staging: 64B rows (32 fp16); one 1KB issue = 16 rows, 4 lanes/row.
  const int srow = lane >> 2;                // 0..15
  const int schk = (lane & 3) ^ (srow & 3);  // 16B chunk
  const _Float16* xg = xf + (size_t)(bm + wave * 32 + srow) * DIM + schk * 8;
  const _Float16* bg = WT + (size_t)(bn + wave * 32 + srow) * DIM + schk * 8;
  const int wb = wave * 2048;  // 32 rows x 64B

  auto issue = [&](char* buf, int k0) {
    ld_lds16(buf + wb,                xg + k0);
    ld_lds16(buf + wb + 1024,         xg + k0 + 16 * DIM);
    ld_lds16(buf + 8192 + wb,         bg + k0);
    ld_lds16(buf + 8192 + wb + 1024,  bg + k0 + 16 * DIM);
  };

  const int swz = (quad ^ (lq & 3)) * 8;  // chunk c of row r at c^(r&3)

  f32x4 acc[4][4];
#pragma unroll
  for (int i = 0; i < 4; ++i)
#pragma unroll
    for (int j = 0; j < 4; ++j) acc[i][j] = (f32x4){0.f, 0.f, 0.f, 0.f};

  char* bufA = smem;
  char* bufB = smem + 16384;
  issue(bufA, 0);
  for (int k0 = 0; k0 < DIM; k0 += 32) {
    char* cur = ((k0 >> 5) & 1) ? bufB : bufA;
    char* nxt = ((k0 >> 5) & 1) ? bufA : bufB;
    __syncthreads();  // drain DMA for cur; all waves done reading nxt
    if (k0 + 32 < DIM) issue(nxt, k0 + 32);
    const _Float16* Xs = (const _Float16*)cur;
    const _Float16* Bs = (const _Float16*)(cur + 8192);
    half8 ah[4];
#pragma unroll
    for (int i = 0; i < 4; ++i)
      ah[i] = *(const half8*)&Xs[(wm + i * 16 + lq) * 32 + swz];
#pragma unroll
    for (int j = 0; j < 4; ++j) {
      half8 bf = *(const half8*)&Bs[(wn + j * 16 + lq) * 32 + swz];
#pragma unroll
      for (int i = 0; i < 4; ++i) acc[i][j] = MFMA_F16K32(ah[i], bf, acc[i][j]);
    }
  }

  if (kind == 2) {  // v -> vT[b][h][d][n], 4 consecutive tokens / 8B store
#pragma unroll
    for (int i = 0; i < 4; ++i)
#pragma unroll
      for (int j = 0; j < 4; ++j) {
        const int c = (bn - 2048) + wn + j * 16 + lq;  // h*64 + d
        const int row0 = bm + wm + i * 16 + quad * 4;  // token
        const int b = row0 >> 11, n = row0 & 2047;
        const int h = c >> 6, d = c & 63;
        half4 o;
#pragma unroll
        for (int r = 0; r < 4; ++r) o[r] = (_Float16)acc[i][j][r];
        *(half4*)(VT + ((size_t)(b * 16 + h) * 64 + d) * 2048 + n) = o;
      }
  } else {
    _Float16* D = (kind == 0) ? qb : kb;
    const int cb = bn & 1023;
#pragma unroll
    for (int i = 0; i < 4; ++i)
#pragma unroll
      for (int j = 0; j < 4; ++j) {
        const int col = cb + wn + j * 16 + lq;
#pragma unroll
        for (int r = 0; r < 4; ++r) {
          const int row = bm + wm + i * 16 + quad * 4 + r;
          D[(size_t)row * 1024 + col] = (_Float16)acc[i][j][r];
        }
      }
  }
}

// ---------------------------------------------------------------------------
// Flash attention attn8: key-parity wave split.
// 8 waves x 32 q-rows, TI=128, TJ=64. Waves 0-3 (group 0) process even
// 64-key tiles, waves 4-7 odd tiles -> 4096 waves total (4/SIMD) at the
// 4-wave kernel's LDS-traffic-per-key (each wave owns 32 q-rows, so K/V
// LDS reads amortize over 2x the MFMA work vs the 16-q version).
// LDS: 4x 8KB K bufs + 4x 8KB V bufs (per-group double buffering) = 64KB
// -> 2 blocks/CU. ONE barrier per interval (2 tiles consumed, 2 staged).
// End: group-1 partials (O^T, m, l) through LDS, group-0 merges (flash
// rescale-combine), transposed store.
// ---------------------------------------------------------------------------
__global__ __launch_bounds__(512, 4) void attn8(
    const _Float16* __restrict__ qb, const _Float16* __restrict__ kb,
    const _Float16* __restrict__ vT, _Float16* __restrict__ ho) {
  __shared__ __align__(16) char smem[65536];
  const int t = threadIdx.x;
  const int lane = t & 63, wave = t >> 6, quad = lane >> 4, lq = lane & 15;
  const int group = wave >> 2, wq = wave & 3;
  const int i0 = blockIdx.x * 128;
  const int bh = blockIdx.y, b = bh >> 4, head = bh & 15;
  const size_t rowbase = (size_t)b * NSEQ;

  // Q fragments (B-operand layout): rows i0 + wq*32 + qt*16 + lq
  half8 qf[2][2];
#pragma unroll
  for (int qt = 0; qt < 2; ++qt) {
    const _Float16* qp =
        qb + (rowbase + i0 + wq * 32 + qt * 16 + lq) * DIM + head * 64 + quad * 8;
    qf[qt][0] = *(const half8*)qp;
    qf[qt][1] = *(const half8*)(qp + 32);
  }

  f32x4 o[2][4];
#pragma unroll
  for (int qt = 0; qt < 2; ++qt)
#pragma unroll
    for (int dt = 0; dt < 4; ++dt) o[qt][dt] = (f32x4){0.f, 0.f, 0.f, 0.f};
  float mrun[2] = {-3.0e38f, -3.0e38f};
  float lrun[2] = {0.f, 0.f};

  // staging: wave stages its own group's next tile.
  // K tile: 64 key-rows x 128B; wave covers rows wq*16..+15 (2 issues).
  // V tile: 64 d-rows x 128B (64 tokens); same row split, same swizzle.
  const int srow = lane >> 3, schk = (lane & 7) ^ srow;
  const _Float16* kgp =
      kb + (rowbase + wq * 16 + srow) * DIM + head * 64 + schk * 8;
  const _Float16* vgp =
      vT + ((size_t)bh * 64 + wq * 16 + srow) * 2048 + schk * 8;

  auto issue = [&](int bsel, int j) {
    char* kd = smem + (group * 2 + bsel) * 8192 + wq * 2048;
    char* vd = kd + 32768;
    ld_lds16(kd,        kgp + (size_t)j * DIM);
    ld_lds16(kd + 1024, kgp + (size_t)(j + 8) * DIM);
    ld_lds16(vd,        vgp + j);
    ld_lds16(vd + 1024, vgp + 8 * 2048 + j);
  };

  const int swzK0 = (quad ^ (lq & 7)) * 8;        // chunk c of row r at c^(r&7)
  const int swzK1 = ((quad + 4) ^ (lq & 7)) * 8;

  issue(0, group * 64);

  for (int p = 0; p < 16; ++p) {
    const int cur = p & 1;
    __syncthreads();  // drain DMA for cur; all waves done reading cur^1
    if (p < 15) issue(cur ^ 1, (2 * p + group) * 64 + 128);
    const _Float16* Khs = (const _Float16*)(smem + (group * 2 + cur) * 8192);
    const _Float16* Vts = (const _Float16*)(smem + 32768 + (group * 2 + cur) * 8192);

    // S^T = K.Q^T over 64 keys (single f16 product)
    f32x4 s[2][4];
    __builtin_amdgcn_s_setprio(1);
#pragma unroll
    for (int nt = 0; nt < 4; ++nt) {
      const int roff = (nt * 16 + lq) * 64;
      half8 k0f = *(const half8*)&Khs[roff + swzK0];
      half8 k1f = *(const half8*)&Khs[roff + swzK1];
#pragma unroll
      for (int qt = 0; qt < 2; ++qt) {
        f32x4 sv = (f32x4){0.f, 0.f, 0.f, 0.f};
        sv = MFMA_F16K32(k0f, qf[qt][0], sv);
        sv = MFMA_F16K32(k1f, qf[qt][1], sv);
        s[qt][nt] = sv;
      }
    }
    __builtin_amdgcn_s_setprio(0);

    // online softmax per qt; q-rows lane-resident (q = lq)
    half4 pbv[2][4];
#pragma unroll
    for (int qt = 0; qt < 2; ++qt) {
      float m0 = fmaxf(fmaxf(s[qt][0][0], s[qt][0][1]),
                       fmaxf(s[qt][0][2], s[qt][0][3]));
      float m1 = fmaxf(fmaxf(s[qt][1][0], s[qt][1][1]),
                       fmaxf(s[qt][1][2], s[qt][1][3]));
      float m2 = fmaxf(fmaxf(s[qt][2][0], s[qt][2][1]),
                       fmaxf(s[qt][2][2], s[qt][2][3]));
      float m3 = fmaxf(fmaxf(s[qt][3][0], s[qt][3][1]),
                       fmaxf(s[qt][3][2], s[qt][3][3]));
      float mx = fmaxf(fmaxf(m0, m1), fmaxf(m2, m3));
      mx = fmaxf(mx, __shfl_xor(mx, 16));
      mx = fmaxf(mx, __shfl_xor(mx, 32));
      const float mn = fmaxf(mrun[qt], mx);
      const float alpha = EXP2F(mrun[qt] - mn);
      mrun[qt] = mn;
      float rs = 0.f;
#pragma unroll
      for (int nt = 0; nt < 4; ++nt) {
        float p0 = EXP2F(s[qt][nt][0] - mn), p1 = EXP2F(s[qt][nt][1] - mn);
        float p2 = EXP2F(s[qt][nt][2] - mn), p3 = EXP2F(s[qt][nt][3] - mn);
        rs += (p0 + p1) + (p2 + p3);
        h2pk lo = CVT_PK(p0, p1);
        h2pk hi = CVT_PK(p2, p3);
        pbv[qt][nt] = (half4){lo[0], lo[1], hi[0], hi[1]};
      }
      rs += __shfl_xor(rs, 16);
      rs += __shfl_xor(rs, 32);
      lrun[qt] = lrun[qt] * alpha + rs;
#pragma unroll
      for (int dt = 0; dt < 4; ++dt) o[qt][dt] *= alpha;
    }

    // O^T += V^T . P^T  (P^T straight from C-layout registers)
    __builtin_amdgcn_s_setprio(1);
#pragma unroll
    for (int dt = 0; dt < 4; ++dt) {
      const int vrow = (dt * 16 + lq) * 64;
#pragma unroll
      for (int ntj = 0; ntj < 4; ++ntj) {
        const int voff =
            vrow + (((2 * ntj + (quad >> 1)) ^ (lq & 7)) * 8) + (quad & 1) * 4;
        half4 va = *(const half4*)&Vts[voff];
        o[0][dt] = MFMA_F16K16(va, pbv[0][ntj], o[0][dt]);
        o[1][dt] = MFMA_F16K16(va, pbv[1][ntj], o[1][dt]);
      }
    }
    __builtin_amdgcn_s_setprio(0);
  }

  // ---- merge the two key-parity partials (waves wq and wq+4 share q-rows)
  float* dump = (float*)smem;  // 4 waves x 64 lanes x 36 f32 = 36864B
  __syncthreads();             // all waves done with final tile reads
  if (group == 1) {
    float* D = dump + wq * 2304 + lane * 36;
#pragma unroll
    for (int qt = 0; qt < 2; ++qt)
#pragma unroll
      for (int dt = 0; dt < 4; ++dt)
        *(f32x4*)(D + (qt * 4 + dt) * 4) = o[qt][dt];
    D[32] = mrun[0]; D[33] = lrun[0]; D[34] = mrun[1]; D[35] = lrun[1];
  }
  __syncthreads();
  _Float16* Ots = (_Float16*)(smem + 40960);  // [128][80] f16 = 20480B
  if (group == 0) {
    const float* D = dump + wq * 2304 + lane * 36;
#pragma unroll
    for (int qt = 0; qt < 2; ++qt) {
      const float m2 = D[32 + qt * 2], l2 = D[33 + qt * 2];
      const float mM = fmaxf(mrun[qt], m2);
      const float f1 = EXP2F(mrun[qt] - mM);
      const float f2 = EXP2F(m2 - mM);
      const float inv = 1.0f / (lrun[qt] * f1 + l2 * f2);
#pragma unroll
      for (int dt = 0; dt < 4; ++dt) {
        f32x4 o2 = *(const f32x4*)(D + (qt * 4 + dt) * 4);
#pragma unroll
        for (int r = 0; r < 4; ++r) {
          const float val = (o[qt][dt][r] * f1 + o2[r] * f2) * inv;
          Ots[(wq * 32 + qt * 16 + lq) * 80 + dt * 16 + quad * 4 + r] =
              (_Float16)val;
        }
      }
    }
  }
  __syncthreads();
  {
    const int row = t >> 2, seg = t & 3;
    const _Float16* src = &Ots[row * 80 + seg * 16];
    half8 o0 = ((const half8*)src)[0], o1 = ((const half8*)src)[1];
    _Float16* dst = ho + (rowbase + i0 + row) * DIM + head * 64 + seg * 16;
    ((half8*)dst)[0] = o0; ((half8*)dst)[1] = o1;
  }
}

// ---------------------------------------------------------------------------
// out = ho(fp16) @ w_out — double-buffered, one barrier per K-iter.
// ---------------------------------------------------------------------------
__global__ __launch_bounds__(256, 4) void gemm_out(
    const _Float16* __restrict__ A, const _Float16* __restrict__ BT,
    float* __restrict__ C) {
  __shared__ __align__(16) char smem[24576];  // 2 bufs: A 4KB | B 8KB
  const int t = threadIdx.x;
  const int lane = t & 63, wave = t >> 6, quad = lane >> 4, lq = lane & 15;
  const int bn = blockIdx.x * 128, bm = blockIdx.y * 64;
  const int wm = (wave >> 1) * 32, wn = (wave & 1) * 64;

  const int bco = (lane & 7) ^ (lane >> 3);
  const int brow = 2 * (lane >> 3) + (bco >> 2);
  const int bcc = bco & 3;
  const _Float16* ag = A + (size_t)(bm + wave * 16 + brow) * DIM + bcc * 8;
  const _Float16* bg = BT + (size_t)(bn + wave * 32 + brow) * DIM + bcc * 8;
  const int swzB = ((((lq & 1) << 2) | quad) ^ ((lq >> 1) & 7)) * 8;

  auto issue = [&](char* buf, int k0) {
    ld_lds16(buf + wave * 1024,               ag + k0);
    ld_lds16(buf + 4096 + wave * 2048,        bg + k0);
    ld_lds16(buf + 4096 + wave * 2048 + 1024, bg + k0 + 16 * DIM);
  };

  f32x4 acc[2][4];
#pragma unroll
  for (int i = 0; i < 2; ++i)
#pragma unroll
    for (int j = 0; j < 4; ++j) acc[i][j] = (f32x4){0.f, 0.f, 0.f, 0.f};

  char* bufA = smem;
  char* bufB = smem + 12288;
  issue(bufA, 0);
  for (int k0 = 0; k0 < DIM; k0 += 32) {
    char* cur = ((k0 >> 5) & 1) ? bufB : bufA;
    char* nxt = ((k0 >> 5) & 1) ? bufA : bufB;
    __syncthreads();
    if (k0 + 32 < DIM) issue(nxt, k0 + 32);
    const _Float16* Ahs = (const _Float16*)cur;
    const _Float16* Bhs = (const _Float16*)(cur + 4096);
    half8 ah[2];
#pragma unroll
    for (int i = 0; i < 2; ++i) {
      const int row = wm + i * 16 + lq;
      ah[i] = *(const half8*)&Ahs[(row >> 1) * 64 + swzB];
    }
#pragma unroll
    for (int j = 0; j < 4; ++j) {
      const int row = wn + j * 16 + lq;
      half8 bf = *(const half8*)&Bhs[(row >> 1) * 64 + swzB];
#pragma unroll
      for (int i = 0; i < 2; ++i) acc[i][j] = MFMA_F16K32(ah[i], bf, acc[i][j]);
    }
  }
#pragma unroll
  for (int i = 0; i < 2; ++i)
#pragma unroll
    for (int j = 0; j < 4; ++j) {
      const int col = bn + wn + j * 16 + lq;
#pragma unroll
      for (int r = 0; r < 4; ++r) {
        const int row = bm + wm + i * 16 + quad * 4 + r;
        C[(size_t)row * 1024 + col] = acc[i][j][r];
      }
    }
}

// ---------------------------------------------------------------------------
extern "C" void kernel_launch(void* const* d_in, const int* in_sizes, int n_in,
                              void* d_out, int out_size, void* d_ws,
                              size_t ws_size, hipStream_t stream) {
  const float* x     = (const float*)d_in[0];
  const float* w_q   = (const float*)d_in[1];
  const float* w_vk  = (const float*)d_in[2];
  const float* w_out = (const float*)d_in[3];
  float* out = (float*)d_out;

  char* w = (char*)d_ws;  // 48 MB used
  _Float16* wT  = (_Float16*)(w);                  // [3072][1024] 6MB
  _Float16* woT = (_Float16*)(w + (6ull << 20));   // [1024][1024] 2MB
  _Float16* qbb = (_Float16*)(w + (8ull << 20));   // [4096][1024] 8MB
  _Float16* kbb = (_Float16*)(w + (16ull << 20));  // [4096][1024] 8MB
  _Float16* vTb = (_Float16*)(w + (24ull << 20));  // [b][h][64][2048] 8MB
  _Float16* hob = (_Float16*)(w + (32ull << 20));  // [4096][1024] 8MB
  _Float16* xfb = (_Float16*)(w + (40ull << 20));  // [4096][1024] 8MB

  dim3 blk(256);
  prep<<<dim3(3072), blk, 0, stream>>>(w_q, w_vk, w_out, x, wT, woT, xfb);
  proj6<<<dim3(24, 32), blk, 0, stream>>>(xfb, wT, qbb, kbb, vTb);
  attn8<<<dim3(16, 32), dim3(512), 0, stream>>>(qbb, kbb, vTb, hob);
  gemm_out<<<dim3(8, 64), blk, 0, stream>>>(hob, woT, out);
}

// Round 5
// 188.708 us; speedup vs baseline: 1.0178x; 1.0022x over previous
//
#include <hip/hip_runtime.h>

typedef _Float16 half4 __attribute__((ext_vector_type(4)));
typedef _Float16 half8 __attribute__((ext_vector_type(8)));
typedef _Float16 h2pk __attribute__((ext_vector_type(2)));
typedef float f32x4 __attribute__((ext_vector_type(4)));

#define MFMA_F16K32(a, b, c) __builtin_amdgcn_mfma_f32_16x16x32_f16(a, b, c, 0, 0, 0)
#define MFMA_F16K16(a, b, c) __builtin_amdgcn_mfma_f32_16x16x16f16(a, b, c, 0, 0, 0)
#define EXP2F(x) __builtin_amdgcn_exp2f(x)
#define CVT_PK(a, b) __builtin_bit_cast(h2pk, __builtin_amdgcn_cvt_pkrtz(a, b))

constexpr int NSEQ = 2048, DIM = 1024;
constexpr float QSCALE = 11.5415603271f;  // 8 * log2(e): logits in log2 units

__device__ __forceinline__ void ld_lds16(void* lds, const void* g) {
  __builtin_amdgcn_global_load_lds(
      (const __attribute__((address_space(1))) void*)g,
      (__attribute__((address_space(3))) void*)lds, 16, 0, 0);
}

// ---------------------------------------------------------------------------
// prep: blocks 0..1023 transpose weights 64x64 -> fp16 WT[3072][1024] / WoT;
// blocks 1024..3071: x -> fp16.
// ---------------------------------------------------------------------------
__global__ __launch_bounds__(256) void prep(
    const float* __restrict__ w_q, const float* __restrict__ w_vk,
    const float* __restrict__ w_out, const float* __restrict__ x,
    _Float16* __restrict__ WT, _Float16* __restrict__ WoT,
    _Float16* __restrict__ xf) {
  const int bid = blockIdx.x;
  const int t = threadIdx.x;
  if (bid >= 1024) {  // ---- x -> fp16 ----
    const size_t i = ((size_t)(bid - 1024) * 256 + t) * 8;
    float4 a = *(const float4*)(x + i), b2 = *(const float4*)(x + i + 4);
    float v[8] = {a.x, a.y, a.z, a.w, b2.x, b2.y, b2.z, b2.w};
    half8 h;
#pragma unroll
    for (int j = 0; j < 8; ++j) h[j] = (_Float16)v[j];
    *(half8*)(xf + i) = h;
    return;
  }
  __shared__ float T[64][65];
  const int bx = bid & 63, k0 = (bid >> 6) * 64;
  const float* src;
  int srcN, n0, dstrow, mode;
  float scale;
  if (bx < 16) {
    src = w_q; srcN = 1024; n0 = bx * 64; dstrow = n0; scale = QSCALE; mode = 0;
  } else if (bx < 48) {
    src = w_vk; srcN = 2048; n0 = (bx - 16) * 64; dstrow = 1024 + n0;
    scale = 1.0f; mode = 0;
  } else {
    src = w_out; srcN = 1024; n0 = (bx - 48) * 64; dstrow = n0;
    scale = 1.0f; mode = 1;
  }
  {
    const int r = t >> 2, c4 = (t & 3) * 16;
    const float* s = src + (size_t)(k0 + r) * srcN + n0 + c4;
    float4 v0 = ((const float4*)s)[0], v1 = ((const float4*)s)[1],
           v2 = ((const float4*)s)[2], v3 = ((const float4*)s)[3];
    *(float4*)&T[r][c4 + 0] = v0;  *(float4*)&T[r][c4 + 4] = v1;
    *(float4*)&T[r][c4 + 8] = v2;  *(float4*)&T[r][c4 + 12] = v3;
  }
  __syncthreads();
  const int rn = t >> 2, kc = (t & 3) * 16;
  half8 hv[2];
#pragma unroll
  for (int hh = 0; hh < 2; ++hh)
#pragma unroll
    for (int j = 0; j < 8; ++j)
      hv[hh][j] = (_Float16)(T[kc + hh * 8 + j][rn] * scale);
  _Float16* d = ((mode == 0) ? WT + (size_t)(dstrow + rn) * 1024
                             : WoT + (size_t)(n0 + rn) * 1024) + k0 + kc;
  *(half8*)d = hv[0]; *(half8*)(d + 8) = hv[1];
}

// ---------------------------------------------------------------------------
// Fused q/k/v projection, all fp16 single-product. 128x128 tile, BK=32,
// double-buffered 2x16KB, ONE barrier per K-iter, 3 blocks/CU.
// kind = bn>>10: 0 -> qb [tok][1024] (weights pre-scaled by QSCALE);
// 1 -> kb [tok][1024]; 2 -> vT fp16 [b][h][d][n], now via LDS transpose so
// global stores are 64B/lane coalesced (was 8B at 4KB stride).
// ---------------------------------------------------------------------------
__global__ __launch_bounds__(256, 3) void proj6(
    const _Float16* __restrict__ xf, const _Float16* __restrict__ WT,
    _Float16* __restrict__ qb, _Float16* __restrict__ kb,
    _Float16* __restrict__ VT) {
  __shared__ __align__(16) char smem[32768];  // 2 bufs x (X 8KB | B 8KB)
  const int t = threadIdx.x;
  const int lane = t & 63, wave = t >> 6, quad = lane >> 4, lq = lane & 15;
  const int bn = blockIdx.x * 128, bm = blockIdx.y * 128;
  const int kind = bn >> 10;
  const int wm = (wave >> 1) * 64, wn = (wave & 1) * 64;

  // staging: 64B rows (32 fp16); one 1KB issue = 16 rows, 4 lanes/row.
  const int srow = lane >> 2;                // 0..15
  const int schk = (lane & 3) ^ (srow & 3);  // 16B chunk
  const _Float16* xg = xf + (size_t)(bm + wave * 32 + srow) * DIM + schk * 8;
  const _Float16* bg = WT + (size_t)(bn + wave * 32 + srow) * DIM + schk * 8;
  const int wb = wave * 2048;  // 32 rows x 64B

  auto issue = [&](char* buf, int k0) {
    ld_lds16(buf + wb,                xg + k0);
    ld_lds16(buf + wb + 1024,         xg + k0 + 16 * DIM);
    ld_lds16(buf + 8192 + wb,         bg + k0);
    ld_lds16(buf + 8192 + wb + 1024,  bg + k0 + 16 * DIM);
  };

  const int swz = (quad ^ (lq & 3)) * 8;  // chunk c of row r at c^(r&3)

  f32x4 acc[4][4];
#pragma unroll
  for (int i = 0; i < 4; ++i)
#pragma unroll
    for (int j = 0; j < 4; ++j) acc[i][j] = (f32x4){0.f, 0.f, 0.f, 0.f};

  char* bufA = smem;
  char* bufB = smem + 16384;
  issue(bufA, 0);
  for (int k0 = 0; k0 < DIM; k0 += 32) {
    char* cur = ((k0 >> 5) & 1) ? bufB : bufA;
    char* nxt = ((k0 >> 5) & 1) ? bufA : bufB;
    __syncthreads();  // drain DMA for cur; all waves done reading nxt
    if (k0 + 32 < DIM) issue(nxt, k0 + 32);
    const _Float16* Xs = (const _Float16*)cur;
    const _Float16* Bs = (const _Float16*)(cur + 8192);
    half8 ah[4];
#pragma unroll
    for (int i = 0; i < 4; ++i)
      ah[i] = *(const half8*)&Xs[(wm + i * 16 + lq) * 32 + swz];
#pragma unroll
    for (int j = 0; j < 4; ++j) {
      half8 bf = *(const half8*)&Bs[(wn + j * 16 + lq) * 32 + swz];
#pragma unroll
      for (int i = 0; i < 4; ++i) acc[i][j] = MFMA_F16K32(ah[i], bf, acc[i][j]);
    }
  }

  if (kind == 2) {
    // v -> vT[b][h][d][n] via LDS transpose; two 64-token passes.
    // Ols: [128 c][68 tok] f16, pitch 68 (bank stride 34 words -> 2-way max).
    _Float16* Ols = (_Float16*)smem;  // 128*68*2 = 17408B <= 32KB
    const int cb = bn - 2048;         // global col base (h*64+d space)
    __syncthreads();                  // all waves done reading K-loop bufs
#pragma unroll
    for (int pass = 0; pass < 2; ++pass) {
      if ((wave >> 1) == pass) {  // waves whose wm == pass*64
#pragma unroll
        for (int i = 0; i < 4; ++i)
#pragma unroll
          for (int j = 0; j < 4; ++j) {
            const int c = wn + j * 16 + lq;    // 0..127
            const int tl = i * 16 + quad * 4;  // token local 0..63
            half4 o;
#pragma unroll
            for (int r = 0; r < 4; ++r) o[r] = (_Float16)acc[i][j][r];
            *(half4*)&Ols[c * 68 + tl] = o;
          }
      }
      __syncthreads();
      {
        const int c = t >> 1, hf = t & 1;  // c 0..127, 32-token half
        const int gcol = cb + c;
        const int tok0 = bm + pass * 64 + hf * 32;
        const int b2 = tok0 >> 11, n2 = tok0 & 2047;
        const _Float16* src = &Ols[c * 68 + hf * 32];
        half8 v0 = ((const half8*)src)[0], v1 = ((const half8*)src)[1],
              v2 = ((const half8*)src)[2], v3 = ((const half8*)src)[3];
        _Float16* dst =
            VT + ((size_t)(b2 * 16 + (gcol >> 6)) * 64 + (gcol & 63)) * 2048 + n2;
        ((half8*)dst)[0] = v0; ((half8*)dst)[1] = v1;
        ((half8*)dst)[2] = v2; ((half8*)dst)[3] = v3;
      }
      __syncthreads();  // before next pass overwrites Ols
    }
  } else {
    _Float16* D = (kind == 0) ? qb : kb;
    const int cb = bn & 1023;
#pragma unroll
    for (int i = 0; i < 4; ++i)
#pragma unroll
      for (int j = 0; j < 4; ++j) {
        const int col = cb + wn + j * 16 + lq;
#pragma unroll
        for (int r = 0; r < 4; ++r) {
          const int row = bm + wm + i * 16 + quad * 4 + r;
          D[(size_t)row * 1024 + col] = (_Float16)acc[i][j][r];
        }
      }
  }
}

// ---------------------------------------------------------------------------
// Flash attention attn8: key-parity wave split (8 waves x 32 q-rows, TJ=64,
// 2 blocks/CU = 4 waves/SIMD). This round: T13 defer-rescale (skip alpha +
// o-rescale unless tile max grows >8 log2-units; P bounded by 2^8, f16-safe),
// hoisted loop-invariant LDS offsets, max3-fusable reduce trees.
// ---------------------------------------------------------------------------
__global__ __launch_bounds__(512, 4) void attn8(
    const _Float16* __restrict__ qb, const _Float16* __restrict__ kb,
    const _Float16* __restrict__ vT, _Float16* __restrict__ ho) {
  __shared__ __align__(16) char smem[65536];
  const int t = threadIdx.x;
  const int lane = t & 63, wave = t >> 6, quad = lane >> 4, lq = lane & 15;
  const int group = wave >> 2, wq = wave & 3;
  const int i0 = blockIdx.x * 128;
  const int bh = blockIdx.y, b = bh >> 4, head = bh & 15;
  const size_t rowbase = (size_t)b * NSEQ;

  // Q fragments (B-operand layout): rows i0 + wq*32 + qt*16 + lq
  half8 qf[2][2];
#pragma unroll
  for (int qt = 0; qt < 2; ++qt) {
    const _Float16* qp =
        qb + (rowbase + i0 + wq * 32 + qt * 16 + lq) * DIM + head * 64 + quad * 8;
    qf[qt][0] = *(const half8*)qp;
    qf[qt][1] = *(const half8*)(qp + 32);
  }

  f32x4 o[2][4];
#pragma unroll
  for (int qt = 0; qt < 2; ++qt)
#pragma unroll
    for (int dt = 0; dt < 4; ++dt) o[qt][dt] = (f32x4){0.f, 0.f, 0.f, 0.f};
  float mrun[2] = {-3.0e38f, -3.0e38f};
  float lrun[2] = {0.f, 0.f};

  // staging: wave stages its own group's next tile.
  const int srow = lane >> 3, schk = (lane & 7) ^ srow;
  const _Float16* kgp =
      kb + (rowbase + wq * 16 + srow) * DIM + head * 64 + schk * 8;
  const _Float16* vgp =
      vT + ((size_t)bh * 64 + wq * 16 + srow) * 2048 + schk * 8;

  auto issue = [&](int bsel, int j) {
    char* kd = smem + (group * 2 + bsel) * 8192 + wq * 2048;
    char* vd = kd + 32768;
    ld_lds16(kd,        kgp + (size_t)j * DIM);
    ld_lds16(kd + 1024, kgp + (size_t)(j + 8) * DIM);
    ld_lds16(vd,        vgp + j);
    ld_lds16(vd + 1024, vgp + 8 * 2048 + j);
  };

  const int swzK0 = (quad ^ (lq & 7)) * 8;        // chunk c of row r at c^(r&7)
  const int swzK1 = ((quad + 4) ^ (lq & 7)) * 8;

  // hoisted loop-invariant LDS offsets
  int koffs[4][2];
#pragma unroll
  for (int nt = 0; nt < 4; ++nt) {
    koffs[nt][0] = (nt * 16 + lq) * 64 + swzK0;
    koffs[nt][1] = (nt * 16 + lq) * 64 + swzK1;
  }
  int voffs[4][4];
#pragma unroll
  for (int dt = 0; dt < 4; ++dt)
#pragma unroll
    for (int ntj = 0; ntj < 4; ++ntj)
      voffs[dt][ntj] = (dt * 16 + lq) * 64 +
                       (((2 * ntj + (quad >> 1)) ^ (lq & 7)) * 8) +
                       (quad & 1) * 4;

  issue(0, group * 64);

  for (int p = 0; p < 16; ++p) {
    const int cur = p & 1;
    __syncthreads();  // drain DMA for cur; all waves done reading cur^1
    if (p < 15) issue(cur ^ 1, (2 * p + group) * 64 + 128);
    const _Float16* Khs = (const _Float16*)(smem + (group * 2 + cur) * 8192);
    const _Float16* Vts = (const _Float16*)(smem + 32768 + (group * 2 + cur) * 8192);

    // S^T = K.Q^T over 64 keys (single f16 product)
    f32x4 s[2][4];
    __builtin_amdgcn_s_setprio(1);
#pragma unroll
    for (int nt = 0; nt < 4; ++nt) {
      half8 k0f = *(const half8*)&Khs[koffs[nt][0]];
      half8 k1f = *(const half8*)&Khs[koffs[nt][1]];
#pragma unroll
      for (int qt = 0; qt < 2; ++qt) {
        f32x4 sv = (f32x4){0.f, 0.f, 0.f, 0.f};
        sv = MFMA_F16K32(k0f, qf[qt][0], sv);
        sv = MFMA_F16K32(k1f, qf[qt][1], sv);
        s[qt][nt] = sv;
      }
    }
    __builtin_amdgcn_s_setprio(0);

    // online softmax per qt; q-rows lane-resident (q = lq)
    half4 pbv[2][4];
#pragma unroll
    for (int qt = 0; qt < 2; ++qt) {
      // max3-fusable tree over 16 lane-resident scores
      float t0 = fmaxf(fmaxf(s[qt][0][0], s[qt][0][1]), s[qt][0][2]);
      float t1 = fmaxf(fmaxf(s[qt][0][3], s[qt][1][0]), s[qt][1][1]);
      float t2 = fmaxf(fmaxf(s[qt][1][2], s[qt][1][3]), s[qt][2][0]);
      float t3 = fmaxf(fmaxf(s[qt][2][1], s[qt][2][2]), s[qt][2][3]);
      float t4 = fmaxf(fmaxf(s[qt][3][0], s[qt][3][1]), s[qt][3][2]);
      float mx = fmaxf(fmaxf(fmaxf(t0, t1), t2),
                       fmaxf(fmaxf(t3, t4), s[qt][3][3]));
      mx = fmaxf(mx, __shfl_xor(mx, 16));
      mx = fmaxf(mx, __shfl_xor(mx, 32));
      // T13 defer-rescale: only rescale when max grows by >8 (log2 units)
      if (!__all(mx - mrun[qt] <= 8.0f)) {
        const float mn = fmaxf(mrun[qt], mx);
        const float alpha = EXP2F(mrun[qt] - mn);
        mrun[qt] = mn;
        lrun[qt] *= alpha;
#pragma unroll
        for (int dt = 0; dt < 4; ++dt) o[qt][dt] *= alpha;
      }
      const float mn2 = mrun[qt];
      float rs = 0.f;
#pragma unroll
      for (int nt = 0; nt < 4; ++nt) {
        float p0 = EXP2F(s[qt][nt][0] - mn2), p1 = EXP2F(s[qt][nt][1] - mn2);
        float p2 = EXP2F(s[qt][nt][2] - mn2), p3 = EXP2F(s[qt][nt][3] - mn2);
        rs += (p0 + p1) + (p2 + p3);
        h2pk lo = CVT_PK(p0, p1);
        h2pk hi = CVT_PK(p2, p3);
        pbv[qt][nt] = (half4){lo[0], lo[1], hi[0], hi[1]};
      }
      rs += __shfl_xor(rs, 16);
      rs += __shfl_xor(rs, 32);
      lrun[qt] += rs;
    }

    // O^T += V^T . P^T  (P^T straight from C-layout registers)
    __builtin_amdgcn_s_setprio(1);
#pragma unroll
    for (int dt = 0; dt < 4; ++dt) {
#pragma unroll
      for (int ntj = 0; ntj < 4; ++ntj) {
        half4 va = *(const half4*)&Vts[voffs[dt][ntj]];
        o[0][dt] = MFMA_F16K16(va, pbv[0][ntj], o[0][dt]);
        o[1][dt] = MFMA_F16K16(va, pbv[1][ntj], o[1][dt]);
      }
    }
    __builtin_amdgcn_s_setprio(0);
  }

  // ---- merge the two key-parity partials (waves wq and wq+4 share q-rows)
  float* dump = (float*)smem;  // 4 waves x 64 lanes x 36 f32 = 36864B
  __syncthreads();             // all waves done with final tile reads
  if (group == 1) {
    float* D = dump + wq * 2304 + lane * 36;
#pragma unroll
    for (int qt = 0; qt < 2; ++qt)
#pragma unroll
      for (int dt = 0; dt < 4; ++dt)
        *(f32x4*)(D + (qt * 4 + dt) * 4) = o[qt][dt];
    D[32] = mrun[0]; D[33] = lrun[0]; D[34] = mrun[1]; D[35] = lrun[1];
  }
  __syncthreads();
  _Float16* Ots = (_Float16*)(smem + 40960);  // [128][80] f16 = 20480B
  if (group == 0) {
    const float* D = dump + wq * 2304 + lane * 36;
#pragma unroll
    for (int qt = 0; qt < 2; ++qt) {
      const float m2 = D[32 + qt * 2], l2 = D[33 + qt * 2];
      const float mM = fmaxf(mrun[qt], m2);
      const float f1 = EXP2F(mrun[qt] - mM);
      const float f2 = EXP2F(m2 - mM);
      const float inv = 1.0f / (lrun[qt] * f1 + l2 * f2);
#pragma unroll
      for (int dt = 0; dt < 4; ++dt) {
        f32x4 o2 = *(const f32x4*)(D + (qt * 4 + dt) * 4);
#pragma unroll
        for (int r = 0; r < 4; ++r) {
          const float val = (o[qt][dt][r] * f1 + o2[r] * f2) * inv;
          Ots[(wq * 32 + qt * 16 + lq) * 80 + dt * 16 + quad * 4 + r] =
              (_Float16)val;
        }
      }
    }
  }
  __syncthreads();
  {
    const int row = t >> 2, seg = t & 3;
    const _Float16* src = &Ots[row * 80 + seg * 16];
    half8 o0 = ((const half8*)src)[0], o1 = ((const half8*)src)[1];
    _Float16* dst = ho + (rowbase + i0 + row) * DIM + head * 64 + seg * 16;
    ((half8*)dst)[0] = o0; ((half8*)dst)[1] = o1;
  }
}

// ---------------------------------------------------------------------------
// out = ho(fp16) @ w_out — proj6-clone 128x128 tile (was 64x128; doubles
// MFMA per ds_read), BK=32 double-buffered, one barrier per K-iter.
// ---------------------------------------------------------------------------
__global__ __launch_bounds__(256, 3) void gemm_out(
    const _Float16* __restrict__ A, const _Float16* __restrict__ BT,
    float* __restrict__ C) {
  __shared__ __align__(16) char smem[32768];  // 2 bufs x (A 8KB | B 8KB)
  const int t = threadIdx.x;
  const int lane = t & 63, wave = t >> 6, quad = lane >> 4, lq = lane & 15;
  const int bn = blockIdx.x * 128, bm = blockIdx.y * 128;
  const int wm = (wave >> 1) * 64, wn = (wave & 1) * 64;

  const int srow = lane >> 2;                // 0..15
  const int schk = (lane & 3) ^ (srow & 3);  // 16B chunk
  const _Float16* ag = A + (size_t)(bm + wave * 32 + srow) * DIM + schk * 8;
  const _Float16* bg = BT + (size_t)(bn + wave * 32 + srow) * DIM + schk * 8;
  const int wb = wave * 2048;  // 32 rows x 64B

  auto issue = [&](char* buf, int k0) {
    ld_lds16(buf + wb,                ag + k0);
    ld_lds16(buf + wb + 1024,         ag + k0 + 16 * DIM);
    ld_lds16(buf + 8192 + wb,         bg + k0);
    ld_lds16(buf + 8192 + wb + 1024,  bg + k0 + 16 * DIM);
  };

  const int swz = (quad ^ (lq & 3)) * 8;  // chunk c of row r at c^(r&3)

  f32x4 acc[4][4];
#pragma unroll
  for (int i = 0; i < 4; ++i)
#pragma unroll
    for (int j = 0; j < 4; ++j) acc[i][j] = (f32x4){0.f, 0.f, 0.f, 0.f};

  char* bufA = smem;
  char* bufB = smem + 16384;
  issue(bufA, 0);
  for (int k0 = 0; k0 < DIM; k0 += 32) {
    char* cur = ((k0 >> 5) & 1) ? bufB : bufA;
    char* nxt = ((k0 >> 5) & 1) ? bufA : bufB;
    __syncthreads();  // drain DMA for cur; all waves done reading nxt
    if (k0 + 32 < DIM) issue(nxt, k0 + 32);
    const _Float16* Ahs = (const _Float16*)cur;
    const _Float16* Bhs = (const _Float16*)(cur + 8192);
    half8 ah[4];
#pragma unroll
    for (int i = 0; i < 4; ++i)
      ah[i] = *(const half8*)&Ahs[(wm + i * 16 + lq) * 32 + swz];
#pragma unroll
    for (int j = 0; j < 4; ++j) {
      half8 bf = *(const half8*)&Bhs[(wn + j * 16 + lq) * 32 + swz];
#pragma unroll
      for (int i = 0; i < 4; ++i) acc[i][j] = MFMA_F16K32(ah[i], bf, acc[i][j]);
    }
  }
#pragma unroll
  for (int i = 0; i < 4; ++i)
#pragma unroll
    for (int j = 0; j < 4; ++j) {
      const int col = bn + wn + j * 16 + lq;
#pragma unroll
      for (int r = 0; r < 4; ++r) {
        const int row = bm + wm + i * 16 + quad * 4 + r;
        C[(size_t)row * 1024 + col] = acc[i][j][r];
      }
    }
}

// ---------------------------------------------------------------------------
extern "C" void kernel_launch(void* const* d_in, const int* in_sizes, int n_in,
                              void* d_out, int out_size, void* d_ws,
                              size_t ws_size, hipStream_t stream) {
  const float* x     = (const float*)d_in[0];
  const float* w_q   = (const float*)d_in[1];
  const float* w_vk  = (const float*)d_in[2];
  const float* w_out = (const float*)d_in[3];
  float* out = (float*)d_out;

  char* w = (char*)d_ws;  // 48 MB used
  _Float16* wT  = (_Float16*)(w);                  // [3072][1024] 6MB
  _Float16* woT = (_Float16*)(w + (6ull << 20));   // [1024][1024] 2MB
  _Float16* qbb = (_Float16*)(w + (8ull << 20));   // [4096][1024] 8MB
  _Float16* kbb = (_Float16*)(w + (16ull << 20));  // [4096][1024] 8MB
  _Float16* vTb = (_Float16*)(w + (24ull << 20));  // [b][h][64][2048] 8MB
  _Float16* hob = (_Float16*)(w + (32ull << 20));  // [4096][1024] 8MB
  _Float16* xfb = (_Float16*)(w + (40ull << 20));  // [4096][1024] 8MB

  dim3 blk(256);
  prep<<<dim3(3072), blk, 0, stream>>>(w_q, w_vk, w_out, x, wT, woT, xfb);
  proj6<<<dim3(24, 32), blk, 0, stream>>>(xfb, wT, qbb, kbb, vTb);
  attn8<<<dim3(16, 32), dim3(512), 0, stream>>>(qbb, kbb, vTb, hob);
  gemm_out<<<dim3(8, 32), blk, 0, stream>>>(hob, woT, out);
}

// Round 6
// 186.037 us; speedup vs baseline: 1.0324x; 1.0144x over previous
//
#include <hip/hip_runtime.h>

typedef _Float16 half4 __attribute__((ext_vector_type(4)));
typedef _Float16 half8 __attribute__((ext_vector_type(8)));
typedef _Float16 h2pk __attribute__((ext_vector_type(2)));
typedef float f32x4 __attribute__((ext_vector_type(4)));

#define MFMA_F16K32(a, b, c) __builtin_amdgcn_mfma_f32_16x16x32_f16(a, b, c, 0, 0, 0)
#define MFMA_F16K16(a, b, c) __builtin_amdgcn_mfma_f32_16x16x16f16(a, b, c, 0, 0, 0)
#define EXP2F(x) __builtin_amdgcn_exp2f(x)
#define CVT_PK(a, b) __builtin_bit_cast(h2pk, __builtin_amdgcn_cvt_pkrtz(a, b))

constexpr int NSEQ = 2048, DIM = 1024;
constexpr float QSCALE = 11.5415603271f;  // 8 * log2(e): logits in log2 units

__device__ __forceinline__ void ld_lds16(void* lds, const void* g) {
  __builtin_amdgcn_global_load_lds(
      (const __attribute__((address_space(1))) void*)g,
      (__attribute__((address_space(3))) void*)lds, 16, 0, 0);
}

// ---------------------------------------------------------------------------
// prep: blocks 0..1023 transpose weights 64x64 -> fp16 WT[3072][1024] / WoT;
// blocks 1024..3071: x -> fp16.
// ---------------------------------------------------------------------------
__global__ __launch_bounds__(256) void prep(
    const float* __restrict__ w_q, const float* __restrict__ w_vk,
    const float* __restrict__ w_out, const float* __restrict__ x,
    _Float16* __restrict__ WT, _Float16* __restrict__ WoT,
    _Float16* __restrict__ xf) {
  const int bid = blockIdx.x;
  const int t = threadIdx.x;
  if (bid >= 1024) {  // ---- x -> fp16 ----
    const size_t i = ((size_t)(bid - 1024) * 256 + t) * 8;
    float4 a = *(const float4*)(x + i), b2 = *(const float4*)(x + i + 4);
    float v[8] = {a.x, a.y, a.z, a.w, b2.x, b2.y, b2.z, b2.w};
    half8 h;
#pragma unroll
    for (int j = 0; j < 8; ++j) h[j] = (_Float16)v[j];
    *(half8*)(xf + i) = h;
    return;
  }
  __shared__ float T[64][65];
  const int bx = bid & 63, k0 = (bid >> 6) * 64;
  const float* src;
  int srcN, n0, dstrow, mode;
  float scale;
  if (bx < 16) {
    src = w_q; srcN = 1024; n0 = bx * 64; dstrow = n0; scale = QSCALE; mode = 0;
  } else if (bx < 48) {
    src = w_vk; srcN = 2048; n0 = (bx - 16) * 64; dstrow = 1024 + n0;
    scale = 1.0f; mode = 0;
  } else {
    src = w_out; srcN = 1024; n0 = (bx - 48) * 64; dstrow = n0;
    scale = 1.0f; mode = 1;
  }
  {
    const int r = t >> 2, c4 = (t & 3) * 16;
    const float* s = src + (size_t)(k0 + r) * srcN + n0 + c4;
    float4 v0 = ((const float4*)s)[0], v1 = ((const float4*)s)[1],
           v2 = ((const float4*)s)[2], v3 = ((const float4*)s)[3];
    *(float4*)&T[r][c4 + 0] = v0;  *(float4*)&T[r][c4 + 4] = v1;
    *(float4*)&T[r][c4 + 8] = v2;  *(float4*)&T[r][c4 + 12] = v3;
  }
  __syncthreads();
  const int rn = t >> 2, kc = (t & 3) * 16;
  half8 hv[2];
#pragma unroll
  for (int hh = 0; hh < 2; ++hh)
#pragma unroll
    for (int j = 0; j < 8; ++j)
      hv[hh][j] = (_Float16)(T[kc + hh * 8 + j][rn] * scale);
  _Float16* d = ((mode == 0) ? WT + (size_t)(dstrow + rn) * 1024
                             : WoT + (size_t)(n0 + rn) * 1024) + k0 + kc;
  *(half8*)d = hv[0]; *(half8*)(d + 8) = hv[1];
}

// ---------------------------------------------------------------------------
// Fused q/k/v projection, all fp16 single-product. 128x128 tile, BK=32,
// double-buffered 2x16KB, ONE barrier per K-iter, now 4 blocks/CU (was 3):
// 16 waves/CU = 4 waves/SIMD.
// kind = bn>>10: 0 -> qb [tok][1024] (weights pre-scaled by QSCALE);
// 1 -> kb [tok][1024]; 2 -> vT fp16 [b][h][d][n] via LDS transpose
// (64B/lane coalesced stores).
// ---------------------------------------------------------------------------
__global__ __launch_bounds__(256, 4) void proj6(
    const _Float16* __restrict__ xf, const _Float16* __restrict__ WT,
    _Float16* __restrict__ qb, _Float16* __restrict__ kb,
    _Float16* __restrict__ VT) {
  __shared__ __align__(16) char smem[32768];  // 2 bufs x (X 8KB | B 8KB)
  const int t = threadIdx.x;
  const int lane = t & 63, wave = t >> 6, quad = lane >> 4, lq = lane & 15;
  const int bn = blockIdx.x * 128, bm = blockIdx.y * 128;
  const int kind = bn >> 10;
  const int wm = (wave >> 1) * 64, wn = (wave & 1) * 64;

  // staging: 64B rows (32 fp16); one 1KB issue = 16 rows, 4 lanes/row.
  const int srow = lane >> 2;                // 0..15
  const int schk = (lane & 3) ^ (srow & 3);  // 16B chunk
  const _Float16* xg = xf + (size_t)(bm + wave * 32 + srow) * DIM + schk * 8;
  const _Float16* bg = WT + (size_t)(bn + wave * 32 + srow) * DIM + schk * 8;
  const int wb = wave * 2048;  // 32 rows x 64B

  auto issue = [&](char* buf, int k0) {
    ld_lds16(buf + wb,                xg + k0);
    ld_lds16(buf + wb + 1024,         xg + k0 + 16 * DIM);
    ld_lds16(buf + 8192 + wb,         bg + k0);
    ld_lds16(buf + 8192 + wb + 1024,  bg + k0 + 16 * DIM);
  };

  const int swz = (quad ^ (lq & 3)) * 8;  // chunk c of row r at c^(r&3)

  f32x4 acc[4][4];
#pragma unroll
  for (int i = 0; i < 4; ++i)
#pragma unroll
    for (int j = 0; j < 4; ++j) acc[i][j] = (f32x4){0.f, 0.f, 0.f, 0.f};

  char* bufA = smem;
  char* bufB = smem + 16384;
  issue(bufA, 0);
  for (int k0 = 0; k0 < DIM; k0 += 32) {
    char* cur = ((k0 >> 5) & 1) ? bufB : bufA;
    char* nxt = ((k0 >> 5) & 1) ? bufA : bufB;
    __syncthreads();  // drain DMA for cur; all waves done reading nxt
    if (k0 + 32 < DIM) issue(nxt, k0 + 32);
    const _Float16* Xs = (const _Float16*)cur;
    const _Float16* Bs = (const _Float16*)(cur + 8192);
    half8 ah[4];
#pragma unroll
    for (int i = 0; i < 4; ++i)
      ah[i] = *(const half8*)&Xs[(wm + i * 16 + lq) * 32 + swz];
#pragma unroll
    for (int j = 0; j < 4; ++j) {
      half8 bf = *(const half8*)&Bs[(wn + j * 16 + lq) * 32 + swz];
#pragma unroll
      for (int i = 0; i < 4; ++i) acc[i][j] = MFMA_F16K32(ah[i], bf, acc[i][j]);
    }
  }

  if (kind == 2) {
    // v -> vT[b][h][d][n] via LDS transpose; two 64-token passes.
    // Ols: [128 c][68 tok] f16, pitch 68 (bank stride 34 words -> 2-way max).
    _Float16* Ols = (_Float16*)smem;  // 128*68*2 = 17408B <= 32KB
    const int cb = bn - 2048;         // global col base (h*64+d space)
    __syncthreads();                  // all waves done reading K-loop bufs
#pragma unroll
    for (int pass = 0; pass < 2; ++pass) {
      if ((wave >> 1) == pass) {  // waves whose wm == pass*64
#pragma unroll
        for (int i = 0; i < 4; ++i)
#pragma unroll
          for (int j = 0; j < 4; ++j) {
            const int c = wn + j * 16 + lq;    // 0..127
            const int tl = i * 16 + quad * 4;  // token local 0..63
            half4 o;
#pragma unroll
            for (int r = 0; r < 4; ++r) o[r] = (_Float16)acc[i][j][r];
            *(half4*)&Ols[c * 68 + tl] = o;
          }
      }
      __syncthreads();
      {
        const int c = t >> 1, hf = t & 1;  // c 0..127, 32-token half
        const int gcol = cb + c;
        const int tok0 = bm + pass * 64 + hf * 32;
        const int b2 = tok0 >> 11, n2 = tok0 & 2047;
        const _Float16* src = &Ols[c * 68 + hf * 32];
        half8 v0 = ((const half8*)src)[0], v1 = ((const half8*)src)[1],
              v2 = ((const half8*)src)[2], v3 = ((const half8*)src)[3];
        _Float16* dst =
            VT + ((size_t)(b2 * 16 + (gcol >> 6)) * 64 + (gcol & 63)) * 2048 + n2;
        ((half8*)dst)[0] = v0; ((half8*)dst)[1] = v1;
        ((half8*)dst)[2] = v2; ((half8*)dst)[3] = v3;
      }
      __syncthreads();  // before next pass overwrites Ols
    }
  } else {
    _Float16* D = (kind == 0) ? qb : kb;
    const int cb = bn & 1023;
#pragma unroll
    for (int i = 0; i < 4; ++i)
#pragma unroll
      for (int j = 0; j < 4; ++j) {
        const int col = cb + wn + j * 16 + lq;
#pragma unroll
        for (int r = 0; r < 4; ++r) {
          const int row = bm + wm + i * 16 + quad * 4 + r;
          D[(size_t)row * 1024 + col] = (_Float16)acc[i][j][r];
        }
      }
  }
}

// ---------------------------------------------------------------------------
// Flash attention attn8 (round-4 body: best measured, 63.6us) + XCD swizzle:
// all 16 q-tiles of one (b,head) land on ONE XCD (xcd = bh&7), so K/V
// (512KB/head; 4 heads x 512KB = 2MB <= 4MB L2/XCD) is fetched from HBM
// once per XCD instead of 8x. DMA loads then hit L2 (~200cy) not HBM
// (~900cy) -- this kernel is latency-bound (no pipe >50%).
// ---------------------------------------------------------------------------
__global__ __launch_bounds__(512, 4) void attn8(
    const _Float16* __restrict__ qb, const _Float16* __restrict__ kb,
    const _Float16* __restrict__ vT, _Float16* __restrict__ ho) {
  __shared__ __align__(16) char smem[65536];
  const int t = threadIdx.x;
  const int lane = t & 63, wave = t >> 6, quad = lane >> 4, lq = lane & 15;
  const int group = wave >> 2, wq = wave & 3;
  // XCD-aware remap: hw linear id -> (i0 tile, bh) with bh&7 == XCD id.
  const int wid = blockIdx.x + 16 * blockIdx.y;  // 0..511
  const int xcd = wid & 7, slot = wid >> 3;      // slot 0..63
  const int i0 = (slot & 15) * 128;
  const int bh = xcd + 8 * (slot >> 4);
  const int b = bh >> 4, head = bh & 15;
  const size_t rowbase = (size_t)b * NSEQ;

  // Q fragments (B-operand layout): rows i0 + wq*32 + qt*16 + lq
  half8 qf[2][2];
#pragma unroll
  for (int qt = 0; qt < 2; ++qt) {
    const _Float16* qp =
        qb + (rowbase + i0 + wq * 32 + qt * 16 + lq) * DIM + head * 64 + quad * 8;
    qf[qt][0] = *(const half8*)qp;
    qf[qt][1] = *(const half8*)(qp + 32);
  }

  f32x4 o[2][4];
#pragma unroll
  for (int qt = 0; qt < 2; ++qt)
#pragma unroll
    for (int dt = 0; dt < 4; ++dt) o[qt][dt] = (f32x4){0.f, 0.f, 0.f, 0.f};
  float mrun[2] = {-3.0e38f, -3.0e38f};
  float lrun[2] = {0.f, 0.f};

  // staging: wave stages its own group's next tile.
  const int srow = lane >> 3, schk = (lane & 7) ^ srow;
  const _Float16* kgp =
      kb + (rowbase + wq * 16 + srow) * DIM + head * 64 + schk * 8;
  const _Float16* vgp =
      vT + ((size_t)bh * 64 + wq * 16 + srow) * 2048 + schk * 8;

  auto issue = [&](int bsel, int j) {
    char* kd = smem + (group * 2 + bsel) * 8192 + wq * 2048;
    char* vd = kd + 32768;
    ld_lds16(kd,        kgp + (size_t)j * DIM);
    ld_lds16(kd + 1024, kgp + (size_t)(j + 8) * DIM);
    ld_lds16(vd,        vgp + j);
    ld_lds16(vd + 1024, vgp + 8 * 2048 + j);
  };

  const int swzK0 = (quad ^ (lq & 7)) * 8;        // chunk c of row r at c^(r&7)
  const int swzK1 = ((quad + 4) ^ (lq & 7)) * 8;

  issue(0, group * 64);

  for (int p = 0; p < 16; ++p) {
    const int cur = p & 1;
    __syncthreads();  // drain DMA for cur; all waves done reading cur^1
    if (p < 15) issue(cur ^ 1, (2 * p + group) * 64 + 128);
    const _Float16* Khs = (const _Float16*)(smem + (group * 2 + cur) * 8192);
    const _Float16* Vts = (const _Float16*)(smem + 32768 + (group * 2 + cur) * 8192);

    // S^T = K.Q^T over 64 keys (single f16 product)
    f32x4 s[2][4];
    __builtin_amdgcn_s_setprio(1);
#pragma unroll
    for (int nt = 0; nt < 4; ++nt) {
      const int roff = (nt * 16 + lq) * 64;
      half8 k0f = *(const half8*)&Khs[roff + swzK0];
      half8 k1f = *(const half8*)&Khs[roff + swzK1];
#pragma unroll
      for (int qt = 0; qt < 2; ++qt) {
        f32x4 sv = (f32x4){0.f, 0.f, 0.f, 0.f};
        sv = MFMA_F16K32(k0f, qf[qt][0], sv);
        sv = MFMA_F16K32(k1f, qf[qt][1], sv);
        s[qt][nt] = sv;
      }
    }
    __builtin_amdgcn_s_setprio(0);

    // online softmax per qt; q-rows lane-resident (q = lq)
    half4 pbv[2][4];
#pragma unroll
    for (int qt = 0; qt < 2; ++qt) {
      float m0 = fmaxf(fmaxf(s[qt][0][0], s[qt][0][1]),
                       fmaxf(s[qt][0][2], s[qt][0][3]));
      float m1 = fmaxf(fmaxf(s[qt][1][0], s[qt][1][1]),
                       fmaxf(s[qt][1][2], s[qt][1][3]));
      float m2 = fmaxf(fmaxf(s[qt][2][0], s[qt][2][1]),
                       fmaxf(s[qt][2][2], s[qt][2][3]));
      float m3 = fmaxf(fmaxf(s[qt][3][0], s[qt][3][1]),
                       fmaxf(s[qt][3][2], s[qt][3][3]));
      float mx = fmaxf(fmaxf(m0, m1), fmaxf(m2, m3));
      mx = fmaxf(mx, __shfl_xor(mx, 16));
      mx = fmaxf(mx, __shfl_xor(mx, 32));
      const float mn = fmaxf(mrun[qt], mx);
      const float alpha = EXP2F(mrun[qt] - mn);
      mrun[qt] = mn;
      float rs = 0.f;
#pragma unroll
      for (int nt = 0; nt < 4; ++nt) {
        float p0 = EXP2F(s[qt][nt][0] - mn), p1 = EXP2F(s[qt][nt][1] - mn);
        float p2 = EXP2F(s[qt][nt][2] - mn), p3 = EXP2F(s[qt][nt][3] - mn);
        rs += (p0 + p1) + (p2 + p3);
        h2pk lo = CVT_PK(p0, p1);
        h2pk hi = CVT_PK(p2, p3);
        pbv[qt][nt] = (half4){lo[0], lo[1], hi[0], hi[1]};
      }
      rs += __shfl_xor(rs, 16);
      rs += __shfl_xor(rs, 32);
      lrun[qt] = lrun[qt] * alpha + rs;
#pragma unroll
      for (int dt = 0; dt < 4; ++dt) o[qt][dt] *= alpha;
    }

    // O^T += V^T . P^T  (P^T straight from C-layout registers)
    __builtin_amdgcn_s_setprio(1);
#pragma unroll
    for (int dt = 0; dt < 4; ++dt) {
      const int vrow = (dt * 16 + lq) * 64;
#pragma unroll
      for (int ntj = 0; ntj < 4; ++ntj) {
        const int voff =
            vrow + (((2 * ntj + (quad >> 1)) ^ (lq & 7)) * 8) + (quad & 1) * 4;
        half4 va = *(const half4*)&Vts[voff];
        o[0][dt] = MFMA_F16K16(va, pbv[0][ntj], o[0][dt]);
        o[1][dt] = MFMA_F16K16(va, pbv[1][ntj], o[1][dt]);
      }
    }
    __builtin_amdgcn_s_setprio(0);
  }

  // ---- merge the two key-parity partials (waves wq and wq+4 share q-rows)
  float* dump = (float*)smem;  // 4 waves x 64 lanes x 36 f32 = 36864B
  __syncthreads();             // all waves done with final tile reads
  if (group == 1) {
    float* D = dump + wq * 2304 + lane * 36;
#pragma unroll
    for (int qt = 0; qt < 2; ++qt)
#pragma unroll
      for (int dt = 0; dt < 4; ++dt)
        *(f32x4*)(D + (qt * 4 + dt) * 4) = o[qt][dt];
    D[32] = mrun[0]; D[33] = lrun[0]; D[34] = mrun[1]; D[35] = lrun[1];
  }
  __syncthreads();
  _Float16* Ots = (_Float16*)(smem + 40960);  // [128][80] f16 = 20480B
  if (group == 0) {
    const float* D = dump + wq * 2304 + lane * 36;
#pragma unroll
    for (int qt = 0; qt < 2; ++qt) {
      const float m2 = D[32 + qt * 2], l2 = D[33 + qt * 2];
      const float mM = fmaxf(mrun[qt], m2);
      const float f1 = EXP2F(mrun[qt] - mM);
      const float f2 = EXP2F(m2 - mM);
      const float inv = 1.0f / (lrun[qt] * f1 + l2 * f2);
#pragma unroll
      for (int dt = 0; dt < 4; ++dt) {
        f32x4 o2 = *(const f32x4*)(D + (qt * 4 + dt) * 4);
#pragma unroll
        for (int r = 0; r < 4; ++r) {
          const float val = (o[qt][dt][r] * f1 + o2[r] * f2) * inv;
          Ots[(wq * 32 + qt * 16 + lq) * 80 + dt * 16 + quad * 4 + r] =
              (_Float16)val;
        }
      }
    }
  }
  __syncthreads();
  {
    const int row = t >> 2, seg = t & 3;
    const _Float16* src = &Ots[row * 80 + seg * 16];
    half8 o0 = ((const half8*)src)[0], o1 = ((const half8*)src)[1];
    _Float16* dst = ho + (rowbase + i0 + row) * DIM + head * 64 + seg * 16;
    ((half8*)dst)[0] = o0; ((half8*)dst)[1] = o1;
  }
}

// ---------------------------------------------------------------------------
// out = ho(fp16) @ w_out — 64x128 tile, 4 blocks/CU (round-4 config; the
// 128^2 variant was 256 blocks = 1 block/CU = latency-bound).
// ---------------------------------------------------------------------------
__global__ __launch_bounds__(256, 4) void gemm_out(
    const _Float16* __restrict__ A, const _Float16* __restrict__ BT,
    float* __restrict__ C) {
  __shared__ __align__(16) char smem[24576];  // 2 bufs: A 4KB | B 8KB
  const int t = threadIdx.x;
  const int lane = t & 63, wave = t >> 6, quad = lane >> 4, lq = lane & 15;
  const int bn = blockIdx.x * 128, bm = blockIdx.y * 64;
  const int wm = (wave >> 1) * 32, wn = (wave & 1) * 64;

  const int bco = (lane & 7) ^ (lane >> 3);
  const int brow = 2 * (lane >> 3) + (bco >> 2);
  const int bcc = bco & 3;
  const _Float16* ag = A + (size_t)(bm + wave * 16 + brow) * DIM + bcc * 8;
  const _Float16* bg = BT + (size_t)(bn + wave * 32 + brow) * DIM + bcc * 8;
  const int swzB = ((((lq & 1) << 2) | quad) ^ ((lq >> 1) & 7)) * 8;

  auto issue = [&](char* buf, int k0) {
    ld_lds16(buf + wave * 1024,               ag + k0);
    ld_lds16(buf + 4096 + wave * 2048,        bg + k0);
    ld_lds16(buf + 4096 + wave * 2048 + 1024, bg + k0 + 16 * DIM);
  };

  f32x4 acc[2][4];
#pragma unroll
  for (int i = 0; i < 2; ++i)
#pragma unroll
    for (int j = 0; j < 4; ++j) acc[i][j] = (f32x4){0.f, 0.f, 0.f, 0.f};

  char* bufA = smem;
  char* bufB = smem + 12288;
  issue(bufA, 0);
  for (int k0 = 0; k0 < DIM; k0 += 32) {
    char* cur = ((k0 >> 5) & 1) ? bufB : bufA;
    char* nxt = ((k0 >> 5) & 1) ? bufA : bufB;
    __syncthreads();
    if (k0 + 32 < DIM) issue(nxt, k0 + 32);
    const _Float16* Ahs = (const _Float16*)cur;
    const _Float16* Bhs = (const _Float16*)(cur + 4096);
    half8 ah[2];
#pragma unroll
    for (int i = 0; i < 2; ++i) {
      const int row = wm + i * 16 + lq;
      ah[i] = *(const half8*)&Ahs[(row >> 1) * 64 + swzB];
    }
#pragma unroll
    for (int j = 0; j < 4; ++j) {
      const int row = wn + j * 16 + lq;
      half8 bf = *(const half8*)&Bhs[(row >> 1) * 64 + swzB];
#pragma unroll
      for (int i = 0; i < 2; ++i) acc[i][j] = MFMA_F16K32(ah[i], bf, acc[i][j]);
    }
  }
#pragma unroll
  for (int i = 0; i < 2; ++i)
#pragma unroll
    for (int j = 0; j < 4; ++j) {
      const int col = bn + wn + j * 16 + lq;
#pragma unroll
      for (int r = 0; r < 4; ++r) {
        const int row = bm + wm + i * 16 + quad * 4 + r;
        C[(size_t)row * 1024 + col] = acc[i][j][r];
      }
    }
}

// ---------------------------------------------------------------------------
extern "C" void kernel_launch(void* const* d_in, const int* in_sizes, int n_in,
                              void* d_out, int out_size, void* d_ws,
                              size_t ws_size, hipStream_t stream) {
  const float* x     = (const float*)d_in[0];
  const float* w_q   = (const float*)d_in[1];
  const float* w_vk  = (const float*)d_in[2];
  const float* w_out = (const float*)d_in[3];
  float* out = (float*)d_out;

  char* w = (char*)d_ws;  // 48 MB used
  _Float16* wT  = (_Float16*)(w);                  // [3072][1024] 6MB
  _Float16* woT = (_Float16*)(w + (6ull << 20));   // [1024][1024] 2MB
  _Float16* qbb = (_Float16*)(w + (8ull << 20));   // [4096][1024] 8MB
  _Float16* kbb = (_Float16*)(w + (16ull << 20));  // [4096][1024] 8MB
  _Float16* vTb = (_Float16*)(w + (24ull << 20));  // [b][h][64][2048] 8MB
  _Float16* hob = (_Float16*)(w + (32ull << 20));  // [4096][1024] 8MB
  _Float16* xfb = (_Float16*)(w + (40ull << 20));  // [4096][1024] 8MB

  dim3 blk(256);
  prep<<<dim3(3072), blk, 0, stream>>>(w_q, w_vk, w_out, x, wT, woT, xfb);
  proj6<<<dim3(24, 32), blk, 0, stream>>>(xfb, wT, qbb, kbb, vTb);
  attn8<<<dim3(16, 32), dim3(512), 0, stream>>>(qbb, kbb, vTb, hob);
  gemm_out<<<dim3(8, 64), blk, 0, stream>>>(hob, woT, out);
}

// Round 7
// 180.005 us; speedup vs baseline: 1.0670x; 1.0335x over previous
//
#include <hip/hip_runtime.h>

typedef _Float16 half4 __attribute__((ext_vector_type(4)));
typedef _Float16 half8 __attribute__((ext_vector_type(8)));
typedef _Float16 h2pk __attribute__((ext_vector_type(2)));
typedef float f32x4 __attribute__((ext_vector_type(4)));

#define MFMA_F16K32(a, b, c) __builtin_amdgcn_mfma_f32_16x16x32_f16(a, b, c, 0, 0, 0)
#define MFMA_F16K16(a, b, c) __builtin_amdgcn_mfma_f32_16x16x16f16(a, b, c, 0, 0, 0)
#define EXP2F(x) __builtin_amdgcn_exp2f(x)
#define CVT_PK(a, b) __builtin_bit_cast(h2pk, __builtin_amdgcn_cvt_pkrtz(a, b))

constexpr int NSEQ = 2048, DIM = 1024;
constexpr float QSCALE = 11.5415603271f;  // 8 * log2(e): logits in log2 units

__device__ __forceinline__ void ld_lds16(void* lds, const void* g) {
  __builtin_amdgcn_global_load_lds(
      (const __attribute__((address_space(1))) void*)g,
      (__attribute__((address_space(3))) void*)lds, 16, 0, 0);
}

// ---------------------------------------------------------------------------
// prep: blocks 0..1023 transpose weights 64x64 -> fp16 WT[3072][1024] / WoT;
// blocks 1024..3071: x -> fp16.
// ---------------------------------------------------------------------------
__global__ __launch_bounds__(256) void prep(
    const float* __restrict__ w_q, const float* __restrict__ w_vk,
    const float* __restrict__ w_out, const float* __restrict__ x,
    _Float16* __restrict__ WT, _Float16* __restrict__ WoT,
    _Float16* __restrict__ xf) {
  const int bid = blockIdx.x;
  const int t = threadIdx.x;
  if (bid >= 1024) {  // ---- x -> fp16 ----
    const size_t i = ((size_t)(bid - 1024) * 256 + t) * 8;
    float4 a = *(const float4*)(x + i), b2 = *(const float4*)(x + i + 4);
    float v[8] = {a.x, a.y, a.z, a.w, b2.x, b2.y, b2.z, b2.w};
    half8 h;
#pragma unroll
    for (int j = 0; j < 8; ++j) h[j] = (_Float16)v[j];
    *(half8*)(xf + i) = h;
    return;
  }
  __shared__ float T[64][65];
  const int bx = bid & 63, k0 = (bid >> 6) * 64;
  const float* src;
  int srcN, n0, dstrow, mode;
  float scale;
  if (bx < 16) {
    src = w_q; srcN = 1024; n0 = bx * 64; dstrow = n0; scale = QSCALE; mode = 0;
  } else if (bx < 48) {
    src = w_vk; srcN = 2048; n0 = (bx - 16) * 64; dstrow = 1024 + n0;
    scale = 1.0f; mode = 0;
  } else {
    src = w_out; srcN = 1024; n0 = (bx - 48) * 64; dstrow = n0;
    scale = 1.0f; mode = 1;
  }
  {
    const int r = t >> 2, c4 = (t & 3) * 16;
    const float* s = src + (size_t)(k0 + r) * srcN + n0 + c4;
    float4 v0 = ((const float4*)s)[0], v1 = ((const float4*)s)[1],
           v2 = ((const float4*)s)[2], v3 = ((const float4*)s)[3];
    *(float4*)&T[r][c4 + 0] = v0;  *(float4*)&T[r][c4 + 4] = v1;
    *(float4*)&T[r][c4 + 8] = v2;  *(float4*)&T[r][c4 + 12] = v3;
  }
  __syncthreads();
  const int rn = t >> 2, kc = (t & 3) * 16;
  half8 hv[2];
#pragma unroll
  for (int hh = 0; hh < 2; ++hh)
#pragma unroll
    for (int j = 0; j < 8; ++j)
      hv[hh][j] = (_Float16)(T[kc + hh * 8 + j][rn] * scale);
  _Float16* d = ((mode == 0) ? WT + (size_t)(dstrow + rn) * 1024
                             : WoT + (size_t)(n0 + rn) * 1024) + k0 + kc;
  *(half8*)d = hv[0]; *(half8*)(d + 8) = hv[1];
}

// ---------------------------------------------------------------------------
// Fused q/k/v projection, all fp16 single-product. 128x128 tile, BK=32,
// double-buffered 2x16KB, ONE barrier per K-iter, 4 blocks/CU.
// kind = bn>>10: 0 -> qb [tok][1024] (weights pre-scaled by QSCALE);
// 1 -> kb [tok][1024]; 2 -> vT fp16 [b][h][d][n] via LDS transpose
// (64B/lane coalesced stores).
// ---------------------------------------------------------------------------
__global__ __launch_bounds__(256, 4) void proj6(
    const _Float16* __restrict__ xf, const _Float16* __restrict__ WT,
    _Float16* __restrict__ qb, _Float16* __restrict__ kb,
    _Float16* __restrict__ VT) {
  __shared__ __align__(16) char smem[32768];  // 2 bufs x (X 8KB | B 8KB)
  const int t = threadIdx.x;
  const int lane = t & 63, wave = t >> 6, quad = lane >> 4, lq = lane & 15;
  const int bn = blockIdx.x * 128, bm = blockIdx.y * 128;
  const int kind = bn >> 10;
  const int wm = (wave >> 1) * 64, wn = (wave & 1) * 64;

  // staging: 64B rows (32 fp16); one 1KB issue = 16 rows, 4 lanes/row.
  const int srow = lane >> 2;                // 0..15
  const int schk = (lane & 3) ^ (srow & 3);  // 16B chunk
  const _Float16* xg = xf + (size_t)(bm + wave * 32 + srow) * DIM + schk * 8;
  const _Float16* bg = WT + (size_t)(bn + wave * 32 + srow) * DIM + schk * 8;
  const int wb = wave * 2048;  // 32 rows x 64B

  auto issue = [&](char* buf, int k0) {
    ld_lds16(buf + wb,                xg + k0);
    ld_lds16(buf + wb + 1024,         xg + k0 + 16 * DIM);
    ld_lds16(buf + 8192 + wb,         bg + k0);
    ld_lds16(buf + 8192 + wb + 1024,  bg + k0 + 16 * DIM);
  };

  const int swz = (quad ^ (lq & 3)) * 8;  // chunk c of row r at c^(r&3)

  f32x4 acc[4][4];
#pragma unroll
  for (int i = 0; i < 4; ++i)
#pragma unroll
    for (int j = 0; j < 4; ++j) acc[i][j] = (f32x4){0.f, 0.f, 0.f, 0.f};

  char* bufA = smem;
  char* bufB = smem + 16384;
  issue(bufA, 0);
  for (int k0 = 0; k0 < DIM; k0 += 32) {
    char* cur = ((k0 >> 5) & 1) ? bufB : bufA;
    char* nxt = ((k0 >> 5) & 1) ? bufA : bufB;
    __syncthreads();  // drain DMA for cur; all waves done reading nxt
    if (k0 + 32 < DIM) issue(nxt, k0 + 32);
    const _Float16* Xs = (const _Float16*)cur;
    const _Float16* Bs = (const _Float16*)(cur + 8192);
    half8 ah[4];
#pragma unroll
    for (int i = 0; i < 4; ++i)
      ah[i] = *(const half8*)&Xs[(wm + i * 16 + lq) * 32 + swz];
#pragma unroll
    for (int j = 0; j < 4; ++j) {
      half8 bf = *(const half8*)&Bs[(wn + j * 16 + lq) * 32 + swz];
#pragma unroll
      for (int i = 0; i < 4; ++i) acc[i][j] = MFMA_F16K32(ah[i], bf, acc[i][j]);
    }
  }

  if (kind == 2) {
    // v -> vT[b][h][d][n] via LDS transpose; two 64-token passes.
    _Float16* Ols = (_Float16*)smem;  // 128*68*2 = 17408B <= 32KB
    const int cb = bn - 2048;         // global col base (h*64+d space)
    __syncthreads();                  // all waves done reading K-loop bufs
#pragma unroll
    for (int pass = 0; pass < 2; ++pass) {
      if ((wave >> 1) == pass) {  // waves whose wm == pass*64
#pragma unroll
        for (int i = 0; i < 4; ++i)
#pragma unroll
          for (int j = 0; j < 4; ++j) {
            const int c = wn + j * 16 + lq;    // 0..127
            const int tl = i * 16 + quad * 4;  // token local 0..63
            half4 o;
#pragma unroll
            for (int r = 0; r < 4; ++r) o[r] = (_Float16)acc[i][j][r];
            *(half4*)&Ols[c * 68 + tl] = o;
          }
      }
      __syncthreads();
      {
        const int c = t >> 1, hf = t & 1;  // c 0..127, 32-token half
        const int gcol = cb + c;
        const int tok0 = bm + pass * 64 + hf * 32;
        const int b2 = tok0 >> 11, n2 = tok0 & 2047;
        const _Float16* src = &Ols[c * 68 + hf * 32];
        half8 v0 = ((const half8*)src)[0], v1 = ((const half8*)src)[1],
              v2 = ((const half8*)src)[2], v3 = ((const half8*)src)[3];
        _Float16* dst =
            VT + ((size_t)(b2 * 16 + (gcol >> 6)) * 64 + (gcol & 63)) * 2048 + n2;
        ((half8*)dst)[0] = v0; ((half8*)dst)[1] = v1;
        ((half8*)dst)[2] = v2; ((half8*)dst)[3] = v3;
      }
      __syncthreads();  // before next pass overwrites Ols
    }
  } else {
    _Float16* D = (kind == 0) ? qb : kb;
    const int cb = bn & 1023;
#pragma unroll
    for (int i = 0; i < 4; ++i)
#pragma unroll
      for (int j = 0; j < 4; ++j) {
        const int col = cb + wn + j * 16 + lq;
#pragma unroll
        for (int r = 0; r < 4; ++r) {
          const int row = bm + wm + i * 16 + quad * 4 + r;
          D[(size_t)row * 1024 + col] = (_Float16)acc[i][j][r];
        }
      }
  }
}

// ---------------------------------------------------------------------------
// Flash attention attn9 = attn8 + K32 PV via per-tile key permutation.
// Within each 64-key tile, K LDS row j holds key kappa(j) (bit-shuffle
// [j5 j3 j2 j4 j1 j0]); V columns stay natural. Then the C-layout S
// fragments concatenate DIRECTLY into K32 B-operands (pa8[blk] =
// [s[2b] pk | s[2b+1] pk]) with zero cross-lane ops, and PV runs
// 16 MFMA K32 + 8 ds_read_b128 per iter (was 32 K16 + 16 ds_read_b64).
// Softmax is key-permutation-invariant. XCD swizzle retained.
// ---------------------------------------------------------------------------
__global__ __launch_bounds__(512, 4) void attn9(
    const _Float16* __restrict__ qb, const _Float16* __restrict__ kb,
    const _Float16* __restrict__ vT, _Float16* __restrict__ ho) {
  __shared__ __align__(16) char smem[65536];
  const int t = threadIdx.x;
  const int lane = t & 63, wave = t >> 6, quad = lane >> 4, lq = lane & 15;
  const int group = wave >> 2, wq = wave & 3;
  // XCD-aware remap: hw linear id -> (i0 tile, bh) with bh&7 == XCD id.
  const int wid = blockIdx.x + 16 * blockIdx.y;  // 0..511
  const int xcd = wid & 7, slot = wid >> 3;      // slot 0..63
  const int i0 = (slot & 15) * 128;
  const int bh = xcd + 8 * (slot >> 4);
  const int b = bh >> 4, head = bh & 15;
  const size_t rowbase = (size_t)b * NSEQ;

  // Q fragments (B-operand layout): rows i0 + wq*32 + qt*16 + lq
  half8 qf[2][2];
#pragma unroll
  for (int qt = 0; qt < 2; ++qt) {
    const _Float16* qp =
        qb + (rowbase + i0 + wq * 32 + qt * 16 + lq) * DIM + head * 64 + quad * 8;
    qf[qt][0] = *(const half8*)qp;
    qf[qt][1] = *(const half8*)(qp + 32);
  }

  f32x4 o[2][4];
#pragma unroll
  for (int qt = 0; qt < 2; ++qt)
#pragma unroll
    for (int dt = 0; dt < 4; ++dt) o[qt][dt] = (f32x4){0.f, 0.f, 0.f, 0.f};
  float mrun[2] = {-3.0e38f, -3.0e38f};
  float lrun[2] = {0.f, 0.f};

  // K staging with kappa row permutation: LDS row j = wq*16 + is*8 + srow
  // holds key kappa(j) = j5*32 + j3*16 + j2*8 + j4*4 + j1j0.
  const int srow = lane >> 3, schk = (lane & 7) ^ srow;
  const int krow = (wq >> 1) * 32 + (wq & 1) * 4 + ((srow & 4) << 1) + (srow & 3);
  const _Float16* kgp =
      kb + (rowbase + krow) * DIM + head * 64 + schk * 8;
  // V staging: [64 d-rows][64 key-cols] natural order, 16B-chunk XOR swizzle.
  const int vrow = lane >> 3;             // 0..7 within 8-row group
  const int vchk = (lane & 7) ^ vrow;     // 16B chunk swizzle (c ^ row&7)
  const _Float16* vgp =
      vT + ((size_t)bh * 64 + wq * 16 + vrow) * 2048 + vchk * 8;

  auto issue = [&](int bsel, int j) {
    char* kd = smem + (group * 2 + bsel) * 8192 + wq * 2048;
    char* vd = kd + 32768;
    ld_lds16(kd,        kgp + (size_t)(j)      * DIM);
    ld_lds16(kd + 1024, kgp + (size_t)(j + 16) * DIM);
    ld_lds16(vd,        vgp + j);
    ld_lds16(vd + 1024, vgp + 8 * 2048 + j);
  };

  const int swzK0 = (quad ^ (lq & 7)) * 8;        // chunk c of row r at c^(r&7)
  const int swzK1 = ((quad + 4) ^ (lq & 7)) * 8;

  issue(0, group * 64);

  for (int p = 0; p < 16; ++p) {
    const int cur = p & 1;
    __syncthreads();  // drain DMA for cur; all waves done reading cur^1
    if (p < 15) issue(cur ^ 1, (2 * p + group) * 64 + 128);
    const _Float16* Khs = (const _Float16*)(smem + (group * 2 + cur) * 8192);
    const _Float16* Vts = (const _Float16*)(smem + 32768 + (group * 2 + cur) * 8192);

    // S^T = K.Q^T over 64 (permuted) keys
    f32x4 s[2][4];
    __builtin_amdgcn_s_setprio(1);
#pragma unroll
    for (int nt = 0; nt < 4; ++nt) {
      const int roff = (nt * 16 + lq) * 64;
      half8 k0f = *(const half8*)&Khs[roff + swzK0];
      half8 k1f = *(const half8*)&Khs[roff + swzK1];
#pragma unroll
      for (int qt = 0; qt < 2; ++qt) {
        f32x4 sv = (f32x4){0.f, 0.f, 0.f, 0.f};
        sv = MFMA_F16K32(k0f, qf[qt][0], sv);
        sv = MFMA_F16K32(k1f, qf[qt][1], sv);
        s[qt][nt] = sv;
      }
    }
    __builtin_amdgcn_s_setprio(0);

    // online softmax per qt; builds K32 B-fragments pa8 directly
    half8 pa8[2][2];
#pragma unroll
    for (int qt = 0; qt < 2; ++qt) {
      float m0 = fmaxf(fmaxf(s[qt][0][0], s[qt][0][1]),
                       fmaxf(s[qt][0][2], s[qt][0][3]));
      float m1 = fmaxf(fmaxf(s[qt][1][0], s[qt][1][1]),
                       fmaxf(s[qt][1][2], s[qt][1][3]));
      float m2 = fmaxf(fmaxf(s[qt][2][0], s[qt][2][1]),
                       fmaxf(s[qt][2][2], s[qt][2][3]));
      float m3 = fmaxf(fmaxf(s[qt][3][0], s[qt][3][1]),
                       fmaxf(s[qt][3][2], s[qt][3][3]));
      float mx = fmaxf(fmaxf(m0, m1), fmaxf(m2, m3));
      mx = fmaxf(mx, __shfl_xor(mx, 16));
      mx = fmaxf(mx, __shfl_xor(mx, 32));
      const float mn = fmaxf(mrun[qt], mx);
      const float alpha = EXP2F(mrun[qt] - mn);
      mrun[qt] = mn;
      float rs = 0.f;
#pragma unroll
      for (int nt = 0; nt < 4; ++nt) {
        float p0 = EXP2F(s[qt][nt][0] - mn), p1 = EXP2F(s[qt][nt][1] - mn);
        float p2 = EXP2F(s[qt][nt][2] - mn), p3 = EXP2F(s[qt][nt][3] - mn);
        rs += (p0 + p1) + (p2 + p3);
        h2pk lo = CVT_PK(p0, p1);
        h2pk hi = CVT_PK(p2, p3);
        const int bb = nt >> 1, e = (nt & 1) * 4;
        pa8[qt][bb][e + 0] = lo[0]; pa8[qt][bb][e + 1] = lo[1];
        pa8[qt][bb][e + 2] = hi[0]; pa8[qt][bb][e + 3] = hi[1];
      }
      rs += __shfl_xor(rs, 16);
      rs += __shfl_xor(rs, 32);
      lrun[qt] = lrun[qt] * alpha + rs;
#pragma unroll
      for (int dt = 0; dt < 4; ++dt) o[qt][dt] *= alpha;
    }

    // O^T += V^T . P^T  — K32: 16 MFMA + 8 ds_read_b128 per iter
    __builtin_amdgcn_s_setprio(1);
#pragma unroll
    for (int dt = 0; dt < 4; ++dt) {
      const int vr2 = (dt * 16 + lq) * 64;
#pragma unroll
      for (int bb = 0; bb < 2; ++bb) {
        const int voff = vr2 + (((bb * 4 + quad) ^ (lq & 7)) * 8);
        half8 va = *(const half8*)&Vts[voff];
        o[0][dt] = MFMA_F16K32(va, pa8[0][bb], o[0][dt]);
        o[1][dt] = MFMA_F16K32(va, pa8[1][bb], o[1][dt]);
      }
    }
    __builtin_amdgcn_s_setprio(0);
  }

  // ---- merge the two key-parity partials (waves wq and wq+4 share q-rows)
  float* dump = (float*)smem;  // 4 waves x 64 lanes x 36 f32 = 36864B
  __syncthreads();             // all waves done with final tile reads
  if (group == 1) {
    float* D = dump + wq * 2304 + lane * 36;
#pragma unroll
    for (int qt = 0; qt < 2; ++qt)
#pragma unroll
      for (int dt = 0; dt < 4; ++dt)
        *(f32x4*)(D + (qt * 4 + dt) * 4) = o[qt][dt];
    D[32] = mrun[0]; D[33] = lrun[0]; D[34] = mrun[1]; D[35] = lrun[1];
  }
  __syncthreads();
  _Float16* Ots = (_Float16*)(smem + 40960);  // [128][80] f16 = 20480B
  if (group == 0) {
    const float* D = dump + wq * 2304 + lane * 36;
#pragma unroll
    for (int qt = 0; qt < 2; ++qt) {
      const float m2 = D[32 + qt * 2], l2 = D[33 + qt * 2];
      const float mM = fmaxf(mrun[qt], m2);
      const float f1 = EXP2F(mrun[qt] - mM);
      const float f2 = EXP2F(m2 - mM);
      const float inv = 1.0f / (lrun[qt] * f1 + l2 * f2);
#pragma unroll
      for (int dt = 0; dt < 4; ++dt) {
        f32x4 o2 = *(const f32x4*)(D + (qt * 4 + dt) * 4);
#pragma unroll
        for (int r = 0; r < 4; ++r) {
          const float val = (o[qt][dt][r] * f1 + o2[r] * f2) * inv;
          Ots[(wq * 32 + qt * 16 + lq) * 80 + dt * 16 + quad * 4 + r] =
              (_Float16)val;
        }
      }
    }
  }
  __syncthreads();
  {
    const int row = t >> 2, seg = t & 3;
    const _Float16* src = &Ots[row * 80 + seg * 16];
    half8 o0 = ((const half8*)src)[0], o1 = ((const half8*)src)[1];
    _Float16* dst = ho + (rowbase + i0 + row) * DIM + head * 64 + seg * 16;
    ((half8*)dst)[0] = o0; ((half8*)dst)[1] = o1;
  }
}

// ---------------------------------------------------------------------------
// out = ho(fp16) @ w_out — 64x128 tile, 4 blocks/CU.
// ---------------------------------------------------------------------------
__global__ __launch_bounds__(256, 4) void gemm_out(
    const _Float16* __restrict__ A, const _Float16* __restrict__ BT,
    float* __restrict__ C) {
  __shared__ __align__(16) char smem[24576];  // 2 bufs: A 4KB | B 8KB
  const int t = threadIdx.x;
  const int lane = t & 63, wave = t >> 6, quad = lane >> 4, lq = lane & 15;
  const int bn = blockIdx.x * 128, bm = blockIdx.y * 64;
  const int wm = (wave >> 1) * 32, wn = (wave & 1) * 64;

  const int bco = (lane & 7) ^ (lane >> 3);
  const int brow = 2 * (lane >> 3) + (bco >> 2);
  const int bcc = bco & 3;
  const _Float16* ag = A + (size_t)(bm + wave * 16 + brow) * DIM + bcc * 8;
  const _Float16* bg = BT + (size_t)(bn + wave * 32 + brow) * DIM + bcc * 8;
  const int swzB = ((((lq & 1) << 2) | quad) ^ ((lq >> 1) & 7)) * 8;

  auto issue = [&](char* buf, int k0) {
    ld_lds16(buf + wave * 1024,               ag + k0);
    ld_lds16(buf + 4096 + wave * 2048,        bg + k0);
    ld_lds16(buf + 4096 + wave * 2048 + 1024, bg + k0 + 16 * DIM);
  };

  f32x4 acc[2][4];
#pragma unroll
  for (int i = 0; i < 2; ++i)
#pragma unroll
    for (int j = 0; j < 4; ++j) acc[i][j] = (f32x4){0.f, 0.f, 0.f, 0.f};

  char* bufA = smem;
  char* bufB = smem + 12288;
  issue(bufA, 0);
  for (int k0 = 0; k0 < DIM; k0 += 32) {
    char* cur = ((k0 >> 5) & 1) ? bufB : bufA;
    char* nxt = ((k0 >> 5) & 1) ? bufA : bufB;
    __syncthreads();
    if (k0 + 32 < DIM) issue(nxt, k0 + 32);
    const _Float16* Ahs = (const _Float16*)cur;
    const _Float16* Bhs = (const _Float16*)(cur + 4096);
    half8 ah[2];
#pragma unroll
    for (int i = 0; i < 2; ++i) {
      const int row = wm + i * 16 + lq;
      ah[i] = *(const half8*)&Ahs[(row >> 1) * 64 + swzB];
    }
#pragma unroll
    for (int j = 0; j < 4; ++j) {
      const int row = wn + j * 16 + lq;
      half8 bf = *(const half8*)&Bhs[(row >> 1) * 64 + swzB];
#pragma unroll
      for (int i = 0; i < 2; ++i) acc[i][j] = MFMA_F16K32(ah[i], bf, acc[i][j]);
    }
  }
#pragma unroll
  for (int i = 0; i < 2; ++i)
#pragma unroll
    for (int j = 0; j < 4; ++j) {
      const int col = bn + wn + j * 16 + lq;
#pragma unroll
      for (int r = 0; r < 4; ++r) {
        const int row = bm + wm + i * 16 + quad * 4 + r;
        C[(size_t)row * 1024 + col] = acc[i][j][r];
      }
    }
}

// ---------------------------------------------------------------------------
extern "C" void kernel_launch(void* const* d_in, const int* in_sizes, int n_in,
                              void* d_out, int out_size, void* d_ws,
                              size_t ws_size, hipStream_t stream) {
  const float* x     = (const float*)d_in[0];
  const float* w_q   = (const float*)d_in[1];
  const float* w_vk  = (const float*)d_in[2];
  const float* w_out = (const float*)d_in[3];
  float* out = (float*)d_out;

  char* w = (char*)d_ws;  // 48 MB used
  _Float16* wT  = (_Float16*)(w);                  // [3072][1024] 6MB
  _Float16* woT = (_Float16*)(w + (6ull << 20));   // [1024][1024] 2MB
  _Float16* qbb = (_Float16*)(w + (8ull << 20));   // [4096][1024] 8MB
  _Float16* kbb = (_Float16*)(w + (16ull << 20));  // [4096][1024] 8MB
  _Float16* vTb = (_Float16*)(w + (24ull << 20));  // [b][h][64][2048] 8MB
  _Float16* hob = (_Float16*)(w + (32ull << 20));  // [4096][1024] 8MB
  _Float16* xfb = (_Float16*)(w + (40ull << 20));  // [4096][1024] 8MB

  dim3 blk(256);
  prep<<<dim3(3072), blk, 0, stream>>>(w_q, w_vk, w_out, x, wT, woT, xfb);
  proj6<<<dim3(24, 32), blk, 0, stream>>>(xfb, wT, qbb, kbb, vTb);
  attn9<<<dim3(16, 32), dim3(512), 0, stream>>>(qbb, kbb, vTb, hob);
  gemm_out<<<dim3(8, 64), blk, 0, stream>>>(hob, woT, out);
}